// Round 6
// baseline (2324.851 us; speedup 1.0000x reference)
//
#include <hip/hip_runtime.h>
#include <hip/hip_fp16.h>
#include <math.h>
#include <string.h>

#define NN 50000
#define NE 400000

#define SK(k) ((((k) >> 2) & 7) << 2)

__device__ __forceinline__ void atomAddF(float* p, float v) { unsafeAtomicAdd(p, v); }
__device__ __forceinline__ void atomAddD(double* p, double v) { unsafeAtomicAdd(p, v); }
__device__ __forceinline__ int atomAddI(int* p, int v) { return atomicAdd(p, v); }

__device__ __forceinline__ float bclane(float v, int l) {
  int i = __builtin_amdgcn_readlane(__builtin_bit_cast(int, v), l);
  return __builtin_bit_cast(float, i);
}

// ---------------- zero fill ----------------
__global__ __launch_bounds__(256) void k_zero(float4* __restrict__ p, int n4) {
  int i = blockIdx.x * 256 + threadIdx.x;
  int s = gridDim.x * 256;
  for (; i < n4; i += s) p[i] = make_float4(0.f, 0.f, 0.f, 0.f);
}

// ---------------- embeddings ----------------
__global__ __launch_bounds__(256) void k_embed_h(const float* __restrict__ hf,
    const float* __restrict__ w, const float* __restrict__ b, float* __restrict__ h) {
  int i = blockIdx.x * 256 + threadIdx.x;
  if (i >= NN * 16) return;
  int n = i >> 4, c0 = (i & 15) * 4;
  float4 acc = *(const float4*)(b + c0);
  const float* row = hf + n * 6;
  #pragma unroll
  for (int k = 0; k < 6; ++k) {
    float x = row[k];
    const float4 wv = *(const float4*)(w + k * 64 + c0);
    acc.x += x * wv.x; acc.y += x * wv.y; acc.z += x * wv.z; acc.w += x * wv.w;
  }
  ((float4*)h)[i] = acc;
}

__global__ __launch_bounds__(256) void k_embed_e(const float* __restrict__ ef2,
    const float* __restrict__ w, const float* __restrict__ b, float* __restrict__ e) {
  int i = blockIdx.x * 256 + threadIdx.x;
  if (i >= NE * 16) return;
  int p = i >> 4, c0 = (i & 15) * 4;
  float2 raw = ((const float2*)ef2)[p];
  float r0 = 1.0f / raw.x;
  float r1 = 1.0f / raw.y;
  float4 acc = *(const float4*)(b + c0);
  const float4 w0 = *(const float4*)(w + c0);
  const float4 w1 = *(const float4*)(w + 64 + c0);
  acc.x += r0 * w0.x + r1 * w1.x;
  acc.y += r0 * w0.y + r1 * w1.y;
  acc.z += r0 * w0.z + r1 * w1.z;
  acc.w += r0 * w0.w + r1 * w1.w;
  ((float4*)e)[i] = acc;
}

// ---------------- CSR build ----------------
__global__ __launch_bounds__(256) void k_deg(const int* __restrict__ dst, int* __restrict__ deg) {
  int i = blockIdx.x * 256 + threadIdx.x;
  if (i < NE) atomAddI(&deg[dst[i]], 1);
}

__global__ __launch_bounds__(1024) void k_scan(int* __restrict__ degcur,
    int* __restrict__ offs, double* __restrict__ stats) {
  __shared__ int wsum[16];
  int t = threadIdx.x;
  int lane = t & 63, w = t >> 6;
  if (t < 256) stats[t] = 0.0;
  int carry = 0;
  for (int base = 0; base < NN; base += 1024) {
    int i = base + t;
    int v = (i < NN) ? degcur[i] : 0;
    int x = v;
    #pragma unroll
    for (int off = 1; off < 64; off <<= 1) {
      int y = __shfl_up(x, off);
      if (lane >= off) x += y;
    }
    if (lane == 63) wsum[w] = x;
    __syncthreads();
    if (w == 0 && lane < 16) {
      int s = wsum[lane];
      #pragma unroll
      for (int off = 1; off < 16; off <<= 1) {
        int y = __shfl_up(s, off);
        if (lane >= off) s += y;
      }
      wsum[lane] = s;
    }
    __syncthreads();
    int wbase = (w > 0) ? wsum[w - 1] : 0;
    int total = wsum[15];
    int excl = carry + wbase + x - v;
    if (i < NN) { offs[i] = excl; degcur[i] = excl; }
    carry += total;
    __syncthreads();
  }
  if (t == 0) offs[NN] = carry;
}

__global__ __launch_bounds__(256) void k_scatter(const int* __restrict__ dst,
    const int* __restrict__ src, const float* __restrict__ e_feat,
    int* __restrict__ cursor,
    int* __restrict__ srcp, int* __restrict__ dstp, float* __restrict__ ef2) {
  int i = blockIdx.x * 256 + threadIdx.x;
  if (i < NE) {
    int d = dst[i];
    int p = atomAddI(&cursor[d], 1);
    srcp[p] = src[i];
    dstp[p] = d;
    ((float2*)ef2)[p] = ((const float2*)e_feat)[i];
  }
}

// ---------------- node GEMM (tiled) + optional fused h-residual ----------------
// MODE==1: during staging, h_new = h + relu(Ah*sc + sh); write h back; GEMM uses h_new.
template <int MODE>
__global__ __launch_bounds__(256) void k_node_gemm(float* __restrict__ h,
    const float* __restrict__ Ah_in, const float* __restrict__ bnp,
    const float* __restrict__ w0, const float* __restrict__ w1,
    const float* __restrict__ w2, const float* __restrict__ w3,
    const float* __restrict__ b0, const float* __restrict__ b1,
    const float* __restrict__ b2, const float* __restrict__ b3,
    float* __restrict__ out) {
  __shared__ float lds[64 * 160 + 64 * 64];
  float* hsT = lds;
  float* wsh = lds + 64 * 160;
  int t = threadIdx.x;
  int n0 = blockIdx.x * 128;
  #pragma unroll
  for (int i = 0; i < 8; ++i) {
    int f = (t + i * 256) * 4;
    int r = f >> 6;
    int k = f & 63;
    int n = n0 + r;
    float4 v = make_float4(0.f, 0.f, 0.f, 0.f);
    if (n < NN) {
      size_t idx = (size_t)n * 64 + k;
      v = *(const float4*)(h + idx);
      if (MODE == 1) {
        float4 av = *(const float4*)(Ah_in + idx);
        float4 sc4 = *(const float4*)(bnp + k);
        float4 sh4 = *(const float4*)(bnp + 64 + k);
        v.x += fmaxf(av.x * sc4.x + sh4.x, 0.f);
        v.y += fmaxf(av.y * sc4.y + sh4.y, 0.f);
        v.z += fmaxf(av.z * sc4.z + sh4.z, 0.f);
        v.w += fmaxf(av.w * sc4.w + sh4.w, 0.f);
        *(float4*)(h + idx) = v;
      }
    }
    int s = SK(k);
    hsT[(k + 0) * 160 + r + s] = v.x;
    hsT[(k + 1) * 160 + r + s] = v.y;
    hsT[(k + 2) * 160 + r + s] = v.z;
    hsT[(k + 3) * 160 + r + s] = v.w;
  }
  int cg = t & 7, rg = t >> 3;
  int cb = cg * 8;
  #pragma unroll 1
  for (int y = 0; y < 4; ++y) {
    const float* W = (y == 0) ? w0 : (y == 1) ? w1 : (y == 2) ? w2 : w3;
    const float* B = (y == 0) ? b0 : (y == 1) ? b1 : (y == 2) ? b2 : b3;
    __syncthreads();
    #pragma unroll
    for (int i = 0; i < 4; ++i)
      ((float4*)wsh)[t + i * 256] = ((const float4*)W)[t + i * 256];
    __syncthreads();
    float acc[4][8];
    #pragma unroll
    for (int r = 0; r < 4; ++r)
      #pragma unroll
      for (int j = 0; j < 8; ++j) acc[r][j] = 0.f;
    #pragma unroll 8
    for (int k = 0; k < 64; ++k) {
      float4 av = *(const float4*)&hsT[k * 160 + SK(k) + rg * 4];
      float4 wv0 = *(const float4*)&wsh[k * 64 + cb];
      float4 wv1 = *(const float4*)&wsh[k * 64 + cb + 4];
      float a[4] = {av.x, av.y, av.z, av.w};
      float w[8] = {wv0.x, wv0.y, wv0.z, wv0.w, wv1.x, wv1.y, wv1.z, wv1.w};
      #pragma unroll
      for (int r = 0; r < 4; ++r)
        #pragma unroll
        for (int j = 0; j < 8; ++j) acc[r][j] += a[r] * w[j];
    }
    float4 bv0 = *(const float4*)(B + cb);
    float4 bv1 = *(const float4*)(B + cb + 4);
    float* oy = out + (size_t)y * NN * 64;
    #pragma unroll
    for (int r = 0; r < 4; ++r) {
      int n = n0 + rg * 4 + r;
      if (n < NN) {
        *(float4*)(oy + (size_t)n * 64 + cb) =
            make_float4(acc[r][0] + bv0.x, acc[r][1] + bv0.y,
                        acc[r][2] + bv0.z, acc[r][3] + bv0.w);
        *(float4*)(oy + (size_t)n * 64 + cb + 4) =
            make_float4(acc[r][4] + bv1.x, acc[r][5] + bv1.y,
                        acc[r][6] + bv1.z, acc[r][7] + bv1.w);
      }
    }
  }
}

// ---------------- fused edge kernel: wave-per-row-pair, readlane GEMM ----------------
// MODE==1: e_new = e + relu(eh16_prev*sc+sh) applied in-register, e written back.
// ehat = e_new@Cw + Cb + Dh[srcp] + Eh[dstp]; store fp16; ESTATS: e-BN stats.
template <int MODE, int ESTATS>
__global__ __launch_bounds__(256, 8) void k_edge_f(float* __restrict__ e,
    __half* __restrict__ eh16,
    const float* __restrict__ Cw, const float* __restrict__ Cb,
    const int* __restrict__ srcp, const int* __restrict__ dstp,
    const float* __restrict__ Dh, const float* __restrict__ Eh,
    const float* __restrict__ bnp, double* __restrict__ stats) {
  __shared__ float cw[4096];
  __shared__ float red[8][64];
  int t = threadIdx.x;
  #pragma unroll
  for (int i = 0; i < 4; ++i)
    ((float4*)cw)[t + i * 256] = ((const float4*)Cw)[t + i * 256];
  __syncthreads();
  int lane = t & 63;
  int w = t >> 6;
  float cbv = Cb[lane];
  float sc = 0.f, sh = 0.f;
  if (MODE == 1) { sc = bnp[128 + lane]; sh = bnp[192 + lane]; }
  float psum = 0.f, psq = 0.f;
  int gw = blockIdx.x * 4 + w;
  int nw = gridDim.x * 4;
  for (int r0 = gw * 2; r0 < NE; r0 += nw * 2) {
    int r1 = r0 + 1;
    size_t i0 = (size_t)r0 * 64 + lane;
    size_t i1 = (size_t)r1 * 64 + lane;
    float ev0 = e[i0];
    float ev1 = e[i1];
    if (MODE == 1) {
      float p0 = __half2float(eh16[i0]);
      float p1 = __half2float(eh16[i1]);
      ev0 += fmaxf(p0 * sc + sh, 0.f);
      ev1 += fmaxf(p1 * sc + sh, 0.f);
      e[i0] = ev0;
      e[i1] = ev1;
    }
    int s0 = srcp[r0], s1 = srcp[r1];
    int d0 = dstp[r0], d1 = dstp[r1];
    float acc0 = cbv + Dh[(size_t)s0 * 64 + lane] + Eh[(size_t)d0 * 64 + lane];
    float acc1 = cbv + Dh[(size_t)s1 * 64 + lane] + Eh[(size_t)d1 * 64 + lane];
    #pragma unroll
    for (int k = 0; k < 64; ++k) {
      float wv = cw[k * 64 + lane];
      acc0 += bclane(ev0, k) * wv;
      acc1 += bclane(ev1, k) * wv;
    }
    if (ESTATS) {
      psum += acc0 + acc1;
      psq += acc0 * acc0 + acc1 * acc1;
    }
    eh16[i0] = __float2half(acc0);
    eh16[i1] = __float2half(acc1);
  }
  if (ESTATS) {
    red[w][lane] = psum;
    red[4 + w][lane] = psq;
    __syncthreads();
    if (w == 0) {
      float s = red[0][lane] + red[1][lane] + red[2][lane] + red[3][lane];
      float q = red[4][lane] + red[5][lane] + red[6][lane] + red[7][lane];
      atomAddD(stats + 128 + lane, (double)s);
      atomAddD(stats + 192 + lane, (double)q);
    }
  }
}

// ---------------- aggregation: one node per wave ----------------
__global__ __launch_bounds__(256, 8) void k_agg(const int* __restrict__ offs,
    const int* __restrict__ srcp, const __half* __restrict__ eh16,
    const float* __restrict__ Bh, float* __restrict__ Ah, double* __restrict__ stats) {
  int t = threadIdx.x;
  int c = t & 63;
  int w = t >> 6;
  int n = blockIdx.x * 4 + w;
  float psum = 0.f, psq = 0.f;
  if (n < NN) {
    int i0 = offs[n], i1 = offs[n + 1];
    float num = 0.f, den = 0.f;
    int i = i0;
    #pragma unroll 1
    for (; i + 1 < i1; i += 2) {
      float x0 = __half2float(eh16[(size_t)i * 64 + c]);
      float x1 = __half2float(eh16[(size_t)(i + 1) * 64 + c]);
      int s0 = srcp[i], s1 = srcp[i + 1];
      float b0 = Bh[(size_t)s0 * 64 + c];
      float b1 = Bh[(size_t)s1 * 64 + c];
      float g0 = 1.0f / (1.0f + __expf(-x0));
      float g1 = 1.0f / (1.0f + __expf(-x1));
      num += g0 * b0 + g1 * b1;
      den += g0 + g1;
    }
    if (i < i1) {
      float x0 = __half2float(eh16[(size_t)i * 64 + c]);
      int s0 = srcp[i];
      float b0 = Bh[(size_t)s0 * 64 + c];
      float g0 = 1.0f / (1.0f + __expf(-x0));
      num += g0 * b0;
      den += g0;
    }
    float v = Ah[(size_t)n * 64 + c] + num / (den + 1e-6f);
    Ah[(size_t)n * 64 + c] = v;
    psum = v; psq = v * v;
  }
  __shared__ float red[256];
  red[t] = psum; __syncthreads();
  if (t < 64) atomAddD(stats + t, (double)(red[t] + red[t + 64] + red[t + 128] + red[t + 192]));
  __syncthreads();
  red[t] = psq; __syncthreads();
  if (t < 64) atomAddD(stats + 64 + t, (double)(red[t] + red[t + 64] + red[t + 128] + red[t + 192]));
}

// ---------------- finalize BN scale/shift; zero stats for next layer ----------------
__global__ void k_bn_final(double* __restrict__ stats,
    const float* __restrict__ hgam, const float* __restrict__ hbet,
    const float* __restrict__ egam, const float* __restrict__ ebet,
    float* __restrict__ bnp) {
  int t = threadIdx.x;
  if (t < 64) {
    double mu = stats[t] * (1.0 / NN);
    double var = stats[64 + t] * (1.0 / NN) - mu * mu;
    float sc = hgam[t] / sqrtf((float)var + 1e-5f);
    bnp[t] = sc;
    bnp[64 + t] = hbet[t] - (float)mu * sc;
  } else if (t < 128) {
    int c = t - 64;
    double mu = stats[128 + c] * (1.0 / NE);
    double var = stats[192 + c] * (1.0 / NE) - mu * mu;
    float sc = egam[c] / sqrtf((float)var + 1e-5f);
    bnp[128 + c] = sc;
    bnp[192 + c] = ebet[c] - (float)mu * sc;
  }
  __syncthreads();
  stats[t] = 0.0;
  stats[t + 128] = 0.0;
}

// ---------------- readout with fused final h-residual ----------------
__global__ __launch_bounds__(256) void k_readout(const float* __restrict__ h,
    const float* __restrict__ Ah, const float* __restrict__ bnp,
    const int* __restrict__ gid, float* __restrict__ hg, float* __restrict__ counts) {
  int t = threadIdx.x;
  int c = t & 63;
  int ro = t >> 6;
  int nbase = blockIdx.x * 64;
  float sc = bnp[c], sh = bnp[64 + c];
  float sum = 0.f, cnt = 0.f;
  int curg = -1;
  #pragma unroll 1
  for (int i = 0; i < 16; ++i) {
    int n = nbase + ro + i * 4;
    if (n >= NN) break;
    int g = gid[n];
    if (g != curg) {
      if (curg >= 0) {
        atomAddF(&hg[curg * 64 + c], sum);
        if (c == 0) atomAddF(&counts[curg], cnt);
      }
      curg = g; sum = 0.f; cnt = 0.f;
    }
    size_t idx = (size_t)n * 64 + c;
    sum += h[idx] + fmaxf(Ah[idx] * sc + sh, 0.f);
    cnt += 1.f;
  }
  if (curg >= 0) {
    atomAddF(&hg[curg * 64 + c], sum);
    if (c == 0) atomAddF(&counts[curg], cnt);
  }
}

// ---------------- final MLP (16 graphs), one block ----------------
__global__ __launch_bounds__(256) void k_mlp(const float* __restrict__ hg, const float* __restrict__ counts,
    const float* __restrict__ state,
    const float* __restrict__ w1, const float* __restrict__ b1,
    const float* __restrict__ w2, const float* __restrict__ b2,
    const float* __restrict__ w3, const float* __restrict__ b3,
    float* __restrict__ out) {
  __shared__ float x0[16][68];
  __shared__ float x1[16][256];
  __shared__ float x2[16][256];
  int t = threadIdx.x;
  for (int idx = t; idx < 16 * 68; idx += 256) {
    int g = idx / 68, c = idx % 68;
    x0[g][c] = (c < 64) ? hg[g * 64 + c] / counts[g] : state[g * 4 + (c - 64)];
  }
  __syncthreads();
  {
    float acc[16];
    float bb = b1[t];
    #pragma unroll
    for (int g = 0; g < 16; ++g) acc[g] = bb;
    for (int k = 0; k < 68; ++k) {
      float w = w1[k * 256 + t];
      #pragma unroll
      for (int g = 0; g < 16; ++g) acc[g] += x0[g][k] * w;
    }
    #pragma unroll
    for (int g = 0; g < 16; ++g) x1[g][t] = fmaxf(acc[g], 0.f);
  }
  __syncthreads();
  {
    float acc[16];
    float bb = b2[t];
    #pragma unroll
    for (int g = 0; g < 16; ++g) acc[g] = bb;
    for (int k = 0; k < 256; ++k) {
      float w = w2[k * 256 + t];
      #pragma unroll
      for (int g = 0; g < 16; ++g) acc[g] += x1[g][k] * w;
    }
    #pragma unroll
    for (int g = 0; g < 16; ++g) x2[g][t] = fmaxf(acc[g], 0.f);
  }
  __syncthreads();
  if (t < 32) {
    int g = t >> 1, o = t & 1;
    float acc = b3[o];
    for (int k = 0; k < 256; ++k) acc += x2[g][k] * w3[k * 2 + o];
    out[g * 2 + o] = tanhf(acc);
  }
}

extern "C" void kernel_launch(void* const* d_in, const int* in_sizes, int n_in,
                              void* d_out, int out_size, void* d_ws, size_t ws_size,
                              hipStream_t stream) {
  const float* state   = (const float*)d_in[0];
  const float* h_feat  = (const float*)d_in[1];
  const float* e_feat  = (const float*)d_in[2];
  const int*   src     = (const int*)d_in[3];
  const int*   dst     = (const int*)d_in[4];
  const int*   gid     = (const int*)d_in[5];
  const float* emb_h_w = (const float*)d_in[6];
  const float* emb_h_b = (const float*)d_in[7];
  const float* emb_e_w = (const float*)d_in[8];
  const float* emb_e_b = (const float*)d_in[9];
  const float* A_w = (const float*)d_in[10];
  const float* A_b = (const float*)d_in[11];
  const float* B_w = (const float*)d_in[12];
  const float* B_b = (const float*)d_in[13];
  const float* C_w = (const float*)d_in[14];
  const float* C_b = (const float*)d_in[15];
  const float* D_w = (const float*)d_in[16];
  const float* D_b = (const float*)d_in[17];
  const float* E_w = (const float*)d_in[18];
  const float* E_b = (const float*)d_in[19];
  const float* bn_h_g = (const float*)d_in[20];
  const float* bn_h_b = (const float*)d_in[21];
  const float* bn_e_g = (const float*)d_in[22];
  const float* bn_e_b = (const float*)d_in[23];
  const float* l1_w = (const float*)d_in[24];
  const float* l1_b = (const float*)d_in[25];
  const float* l2_w = (const float*)d_in[26];
  const float* l2_b = (const float*)d_in[27];
  const float* l3_w = (const float*)d_in[28];
  const float* l3_b = (const float*)d_in[29];

  float* wsp = (float*)d_ws;

  const size_t F_H = (size_t)NN * 64;
  const size_t F_E = (size_t)NE * 64;
  size_t off = 0;
  float* h     = wsp + off; off += F_H;
  float* e     = wsp + off; off += F_E;
  float* Ah    = wsp + off; off += F_H;
  float* Bh    = wsp + off; off += F_H;
  float* Dh    = wsp + off; off += F_H;
  float* Eh    = wsp + off; off += F_H;
  __half* eh16 = (__half*)(wsp + off); off += F_E / 2;
  float* ef2   = (float*)eh16;  // overlay: raw CSR-ordered e_feat pairs
  int* srcp    = (int*)(wsp + off); off += NE;
  int* dstp    = (int*)(wsp + off); off += NE;
  int* offs    = (int*)(wsp + off); off += NN + 4;
  int* degcur  = (int*)(wsp + off); off += NN;
  double* stats = (double*)(wsp + off); off += 512;
  float* bnp    = wsp + off; off += 256;
  float* hg     = wsp + off; off += 1024;
  float* counts = hg + 1024; off += 16;
  const size_t need = off * sizeof(float);
  if (ws_size < need) return;

  // CSR build + embeds
  k_zero<<<64, 256, 0, stream>>>((float4*)degcur, NN / 4);
  k_deg<<<(NE + 255) / 256, 256, 0, stream>>>(dst, degcur);
  k_scan<<<1, 1024, 0, stream>>>(degcur, offs, stats);
  k_scatter<<<(NE + 255) / 256, 256, 0, stream>>>(dst, src, e_feat, degcur, srcp, dstp, ef2);
  k_embed_e<<<(NE * 16 + 255) / 256, 256, 0, stream>>>(ef2, emb_e_w, emb_e_b, e);
  k_embed_h<<<(NN * 16 + 255) / 256, 256, 0, stream>>>(h_feat, emb_h_w, emb_h_b, h);

  const int GEDGE = 2048;
  for (int l = 0; l < 3; ++l) {
    if (l == 0)
      k_node_gemm<0><<<(NN + 127) / 128, 256, 0, stream>>>(h, Ah, bnp,
          A_w, B_w, D_w, E_w, A_b, B_b, D_b, E_b, Ah);
    else
      k_node_gemm<1><<<(NN + 127) / 128, 256, 0, stream>>>(h, Ah, bnp,
          A_w + l * 4096, B_w + l * 4096, D_w + l * 4096, E_w + l * 4096,
          A_b + l * 64, B_b + l * 64, D_b + l * 64, E_b + l * 64, Ah);
    if (l == 0)
      k_edge_f<0, 1><<<GEDGE, 256, 0, stream>>>(e, eh16, C_w, C_b,
          srcp, dstp, Dh, Eh, bnp, stats);
    else if (l == 1)
      k_edge_f<1, 1><<<GEDGE, 256, 0, stream>>>(e, eh16, C_w + 4096, C_b + 64,
          srcp, dstp, Dh, Eh, bnp, stats);
    else
      k_edge_f<1, 0><<<GEDGE, 256, 0, stream>>>(e, eh16, C_w + 8192, C_b + 128,
          srcp, dstp, Dh, Eh, bnp, stats);
    k_agg<<<(NN + 3) / 4, 256, 0, stream>>>(offs, srcp, eh16, Bh, Ah, stats);
    k_bn_final<<<1, 128, 0, stream>>>(stats, bn_h_g + l * 64, bn_h_b + l * 64,
        bn_e_g + l * 64, bn_e_b + l * 64, bnp);
  }
  k_zero<<<2, 256, 0, stream>>>((float4*)hg, (1024 + 16) / 4);
  k_readout<<<(NN + 63) / 64, 256, 0, stream>>>(h, Ah, bnp, gid, hg, counts);
  k_mlp<<<1, 256, 0, stream>>>(hg, counts, state,
      l1_w, l1_b, l2_w, l2_b, l3_w, l3_b, (float*)d_out);
}

// Round 7
// 1101.955 us; speedup vs baseline: 2.1098x; 2.1098x over previous
//
#include <hip/hip_runtime.h>
#include <hip/hip_fp16.h>
#include <math.h>
#include <string.h>

#define NN 50000
#define NE 400000

#define SK(k) ((((k) >> 2) & 7) << 2)

__device__ __forceinline__ void atomAddF(float* p, float v) { unsafeAtomicAdd(p, v); }
__device__ __forceinline__ void atomAddD(double* p, double v) { unsafeAtomicAdd(p, v); }
__device__ __forceinline__ int atomAddI(int* p, int v) { return atomicAdd(p, v); }

__device__ __forceinline__ float2 up2h(unsigned v) {
  __half2 h; memcpy(&h, &v, 4); return __half22float2(h);
}
__device__ __forceinline__ unsigned pk2h(float a, float b) {
  __half2 h = __floats2half2_rn(a, b);
  unsigned v; memcpy(&v, &h, 4); return v;
}

// ---------------- zero fill ----------------
__global__ __launch_bounds__(256) void k_zero(float4* __restrict__ p, int n4) {
  int i = blockIdx.x * 256 + threadIdx.x;
  int s = gridDim.x * 256;
  for (; i < n4; i += s) p[i] = make_float4(0.f, 0.f, 0.f, 0.f);
}

// ---------------- embeddings ----------------
__global__ __launch_bounds__(256) void k_embed_h(const float* __restrict__ hf,
    const float* __restrict__ w, const float* __restrict__ b, float* __restrict__ h) {
  int i = blockIdx.x * 256 + threadIdx.x;
  if (i >= NN * 16) return;
  int n = i >> 4, c0 = (i & 15) * 4;
  float4 acc = *(const float4*)(b + c0);
  const float* row = hf + n * 6;
  #pragma unroll
  for (int k = 0; k < 6; ++k) {
    float x = row[k];
    const float4 wv = *(const float4*)(w + k * 64 + c0);
    acc.x += x * wv.x; acc.y += x * wv.y; acc.z += x * wv.z; acc.w += x * wv.w;
  }
  ((float4*)h)[i] = acc;
}

__global__ __launch_bounds__(256) void k_embed_e(const float* __restrict__ ef2,
    const float* __restrict__ w, const float* __restrict__ b, float* __restrict__ e) {
  int i = blockIdx.x * 256 + threadIdx.x;
  if (i >= NE * 16) return;
  int p = i >> 4, c0 = (i & 15) * 4;
  float2 raw = ((const float2*)ef2)[p];
  float r0 = 1.0f / raw.x;
  float r1 = 1.0f / raw.y;
  float4 acc = *(const float4*)(b + c0);
  const float4 w0 = *(const float4*)(w + c0);
  const float4 w1 = *(const float4*)(w + 64 + c0);
  acc.x += r0 * w0.x + r1 * w1.x;
  acc.y += r0 * w0.y + r1 * w1.y;
  acc.z += r0 * w0.z + r1 * w1.z;
  acc.w += r0 * w0.w + r1 * w1.w;
  ((float4*)e)[i] = acc;
}

// ---------------- CSR build ----------------
__global__ __launch_bounds__(256) void k_deg(const int* __restrict__ dst, int* __restrict__ deg) {
  int i = blockIdx.x * 256 + threadIdx.x;
  if (i < NE) atomAddI(&deg[dst[i]], 1);
}

__global__ __launch_bounds__(1024) void k_scan(int* __restrict__ degcur,
    int* __restrict__ offs, double* __restrict__ stats) {
  __shared__ int wsum[16];
  int t = threadIdx.x;
  int lane = t & 63, w = t >> 6;
  if (t < 256) stats[t] = 0.0;
  int carry = 0;
  for (int base = 0; base < NN; base += 1024) {
    int i = base + t;
    int v = (i < NN) ? degcur[i] : 0;
    int x = v;
    #pragma unroll
    for (int off = 1; off < 64; off <<= 1) {
      int y = __shfl_up(x, off);
      if (lane >= off) x += y;
    }
    if (lane == 63) wsum[w] = x;
    __syncthreads();
    if (w == 0 && lane < 16) {
      int s = wsum[lane];
      #pragma unroll
      for (int off = 1; off < 16; off <<= 1) {
        int y = __shfl_up(s, off);
        if (lane >= off) s += y;
      }
      wsum[lane] = s;
    }
    __syncthreads();
    int wbase = (w > 0) ? wsum[w - 1] : 0;
    int total = wsum[15];
    int excl = carry + wbase + x - v;
    if (i < NN) { offs[i] = excl; degcur[i] = excl; }
    carry += total;
    __syncthreads();
  }
  if (t == 0) offs[NN] = carry;
}

__global__ __launch_bounds__(256) void k_scatter(const int* __restrict__ dst,
    const int* __restrict__ src, const float* __restrict__ e_feat,
    int* __restrict__ cursor,
    int* __restrict__ srcp, int* __restrict__ dstp, float* __restrict__ ef2) {
  int i = blockIdx.x * 256 + threadIdx.x;
  if (i < NE) {
    int d = dst[i];
    int p = atomAddI(&cursor[d], 1);
    srcp[p] = src[i];
    dstp[p] = d;
    ((float2*)ef2)[p] = ((const float2*)e_feat)[i];
  }
}

// ---------------- node GEMM, 64-row tile + optional fused h-residual ----------------
// MODE==1: during staging, h_new = h + relu(Ah*sc + sh); write h back; GEMM uses h_new.
template <int MODE>
__global__ __launch_bounds__(256) void k_node_gemm(float* __restrict__ h,
    const float* __restrict__ Ah_in, const float* __restrict__ bnp,
    const float* __restrict__ w0, const float* __restrict__ w1,
    const float* __restrict__ w2, const float* __restrict__ w3,
    const float* __restrict__ b0, const float* __restrict__ b1,
    const float* __restrict__ b2, const float* __restrict__ b3,
    float* __restrict__ out) {
  __shared__ float hsT[64 * 72];
  __shared__ float wsh[64 * 64];
  int t = threadIdx.x;
  int n0 = blockIdx.x * 64;
  #pragma unroll
  for (int i = 0; i < 4; ++i) {
    int f = (t + i * 256) * 4;
    int r = f >> 6;
    int k = f & 63;
    int n = n0 + r;
    float4 v = make_float4(0.f, 0.f, 0.f, 0.f);
    if (n < NN) {
      size_t idx = (size_t)n * 64 + k;
      v = *(const float4*)(h + idx);
      if (MODE == 1) {
        float4 av = *(const float4*)(Ah_in + idx);
        float4 sc4 = *(const float4*)(bnp + k);
        float4 sh4 = *(const float4*)(bnp + 64 + k);
        v.x += fmaxf(av.x * sc4.x + sh4.x, 0.f);
        v.y += fmaxf(av.y * sc4.y + sh4.y, 0.f);
        v.z += fmaxf(av.z * sc4.z + sh4.z, 0.f);
        v.w += fmaxf(av.w * sc4.w + sh4.w, 0.f);
        *(float4*)(h + idx) = v;
      }
    }
    int s = SK(k);
    hsT[(k + 0) * 72 + r + s] = v.x;
    hsT[(k + 1) * 72 + r + s] = v.y;
    hsT[(k + 2) * 72 + r + s] = v.z;
    hsT[(k + 3) * 72 + r + s] = v.w;
  }
  int cg = t & 7, rg = t >> 3;   // rg 0..31 (2 rows each), cg 0..7 (8 cols)
  int cb = cg * 8;
  #pragma unroll 1
  for (int y = 0; y < 4; ++y) {
    const float* W = (y == 0) ? w0 : (y == 1) ? w1 : (y == 2) ? w2 : w3;
    const float* B = (y == 0) ? b0 : (y == 1) ? b1 : (y == 2) ? b2 : b3;
    __syncthreads();
    #pragma unroll
    for (int i = 0; i < 4; ++i)
      ((float4*)wsh)[t + i * 256] = ((const float4*)W)[t + i * 256];
    __syncthreads();
    float acc[2][8];
    #pragma unroll
    for (int r = 0; r < 2; ++r)
      #pragma unroll
      for (int j = 0; j < 8; ++j) acc[r][j] = 0.f;
    #pragma unroll 8
    for (int k = 0; k < 64; ++k) {
      float2 av = *(const float2*)&hsT[k * 72 + SK(k) + rg * 2];
      float4 wv0 = *(const float4*)&wsh[k * 64 + cb];
      float4 wv1 = *(const float4*)&wsh[k * 64 + cb + 4];
      float a[2] = {av.x, av.y};
      float w[8] = {wv0.x, wv0.y, wv0.z, wv0.w, wv1.x, wv1.y, wv1.z, wv1.w};
      #pragma unroll
      for (int r = 0; r < 2; ++r)
        #pragma unroll
        for (int j = 0; j < 8; ++j) acc[r][j] += a[r] * w[j];
    }
    float4 bv0 = *(const float4*)(B + cb);
    float4 bv1 = *(const float4*)(B + cb + 4);
    float* oy = out + (size_t)y * NN * 64;
    #pragma unroll
    for (int r = 0; r < 2; ++r) {
      int n = n0 + rg * 2 + r;
      if (n < NN) {
        *(float4*)(oy + (size_t)n * 64 + cb) =
            make_float4(acc[r][0] + bv0.x, acc[r][1] + bv0.y,
                        acc[r][2] + bv0.z, acc[r][3] + bv0.w);
        *(float4*)(oy + (size_t)n * 64 + cb + 4) =
            make_float4(acc[r][4] + bv1.x, acc[r][5] + bv1.y,
                        acc[r][6] + bv1.z, acc[r][7] + bv1.w);
      }
    }
  }
}

// ---------------- fused edge kernel, 64-row tile ----------------
// MODE==1: e_new = e + relu(eh16_prev*sc+sh) during staging; EWRITE: write e back.
// ehat = e_new@Cw + Cb + Dh[srcp] + Eh[dstp]; store fp16; ESTATS: e-BN stats.
template <int MODE, int ESTATS, int EWRITE>
__global__ __launch_bounds__(256) void k_edge_f(float* __restrict__ e,
    __half* __restrict__ eh16,
    const float* __restrict__ Cw, const float* __restrict__ Cb,
    const int* __restrict__ srcp, const int* __restrict__ dstp,
    const float* __restrict__ Dh, const float* __restrict__ Eh,
    const float* __restrict__ bnp, double* __restrict__ stats) {
  __shared__ float esT[64 * 72];
  __shared__ float cw[64 * 64];
  int t = threadIdx.x;
  int e0 = blockIdx.x * 64;
  #pragma unroll
  for (int i = 0; i < 4; ++i)
    ((float4*)cw)[t + i * 256] = ((const float4*)Cw)[t + i * 256];
  #pragma unroll
  for (int i = 0; i < 4; ++i) {
    int f = (t + i * 256) * 4;
    int r = f >> 6;
    int k = f & 63;
    size_t idx = (size_t)(e0 + r) * 64 + k;
    float4 v = *(const float4*)(e + idx);
    if (MODE == 1) {
      uint2 hh = *(const uint2*)(eh16 + idx);
      float2 fa = up2h(hh.x), fb = up2h(hh.y);
      float4 sc4 = *(const float4*)(bnp + 128 + k);
      float4 sh4 = *(const float4*)(bnp + 192 + k);
      v.x += fmaxf(fa.x * sc4.x + sh4.x, 0.f);
      v.y += fmaxf(fa.y * sc4.y + sh4.y, 0.f);
      v.z += fmaxf(fb.x * sc4.z + sh4.z, 0.f);
      v.w += fmaxf(fb.y * sc4.w + sh4.w, 0.f);
      if (EWRITE) *(float4*)(e + idx) = v;
    }
    int s = SK(k);
    esT[(k + 0) * 72 + r + s] = v.x;
    esT[(k + 1) * 72 + r + s] = v.y;
    esT[(k + 2) * 72 + r + s] = v.z;
    esT[(k + 3) * 72 + r + s] = v.w;
  }
  __syncthreads();
  int cg = t & 7, rg = t >> 3;
  int cb = cg * 8;
  float acc[2][8];
  #pragma unroll
  for (int r = 0; r < 2; ++r)
    #pragma unroll
    for (int j = 0; j < 8; ++j) acc[r][j] = 0.f;
  #pragma unroll 8
  for (int k = 0; k < 64; ++k) {
    float2 av = *(const float2*)&esT[k * 72 + SK(k) + rg * 2];
    float4 wv0 = *(const float4*)&cw[k * 64 + cb];
    float4 wv1 = *(const float4*)&cw[k * 64 + cb + 4];
    float a[2] = {av.x, av.y};
    float w[8] = {wv0.x, wv0.y, wv0.z, wv0.w, wv1.x, wv1.y, wv1.z, wv1.w};
    #pragma unroll
    for (int r = 0; r < 2; ++r)
      #pragma unroll
      for (int j = 0; j < 8; ++j) acc[r][j] += a[r] * w[j];
  }
  float4 cb0 = *(const float4*)(Cb + cb);
  float4 cb1 = *(const float4*)(Cb + cb + 4);
  float cbv[8] = {cb0.x, cb0.y, cb0.z, cb0.w, cb1.x, cb1.y, cb1.z, cb1.w};
  float psum[8], psq[8];
  #pragma unroll
  for (int j = 0; j < 8; ++j) { psum[j] = 0.f; psq[j] = 0.f; }
  #pragma unroll
  for (int r = 0; r < 2; ++r) {
    int p = e0 + rg * 2 + r;
    int sN = srcp[p], dN = dstp[p];
    const float* dp = Dh + (size_t)sN * 64 + cb;
    const float* ep = Eh + (size_t)dN * 64 + cb;
    float4 d0 = *(const float4*)dp, d1 = *(const float4*)(dp + 4);
    float4 q0 = *(const float4*)ep, q1 = *(const float4*)(ep + 4);
    float dd[8] = {d0.x, d0.y, d0.z, d0.w, d1.x, d1.y, d1.z, d1.w};
    float qq[8] = {q0.x, q0.y, q0.z, q0.w, q1.x, q1.y, q1.z, q1.w};
    float ev[8];
    #pragma unroll
    for (int j = 0; j < 8; ++j) {
      float v = acc[r][j] + cbv[j] + dd[j] + qq[j];
      ev[j] = v;
      if (ESTATS) { psum[j] += v; psq[j] += v * v; }
    }
    uint4 u;
    u.x = pk2h(ev[0], ev[1]);
    u.y = pk2h(ev[2], ev[3]);
    u.z = pk2h(ev[4], ev[5]);
    u.w = pk2h(ev[6], ev[7]);
    *(uint4*)(eh16 + (size_t)p * 64 + cb) = u;
  }
  if (ESTATS) {
    __syncthreads();  // esT reuse for stats reduce
    #pragma unroll
    for (int j = 0; j < 8; ++j) {
      esT[rg * 65 + cb + j] = psum[j];
      esT[2304 + rg * 65 + cb + j] = psq[j];
    }
    __syncthreads();
    if (t < 64) {
      float s = 0.f, q = 0.f;
      #pragma unroll
      for (int i = 0; i < 32; ++i) { s += esT[i * 65 + t]; q += esT[2304 + i * 65 + t]; }
      atomAddD(stats + 128 + t, (double)s);
      atomAddD(stats + 192 + t, (double)q);
    }
  }
}

// ---------------- aggregation (round-5 style: 16 nodes/block) ----------------
__global__ __launch_bounds__(256) void k_agg(const int* __restrict__ offs,
    const int* __restrict__ srcp, const __half* __restrict__ eh16,
    const float* __restrict__ Bh, float* __restrict__ Ah, double* __restrict__ stats) {
  int t = threadIdx.x;
  int c = t & 63;
  int g = t >> 6;
  float psum = 0.f, psq = 0.f;
  #pragma unroll 1
  for (int sub = 0; sub < 4; ++sub) {
    int n = blockIdx.x * 16 + g * 4 + sub;
    if (n < NN) {
      int i0 = offs[n], i1 = offs[n + 1];
      float num = 0.f, den = 0.f;
      int i = i0;
      #pragma unroll 1
      for (; i + 1 < i1; i += 2) {
        float x0 = __half2float(eh16[(size_t)i * 64 + c]);
        float x1 = __half2float(eh16[(size_t)(i + 1) * 64 + c]);
        int s0 = srcp[i], s1 = srcp[i + 1];
        float b0 = Bh[(size_t)s0 * 64 + c];
        float b1 = Bh[(size_t)s1 * 64 + c];
        float g0 = 1.0f / (1.0f + __expf(-x0));
        float g1 = 1.0f / (1.0f + __expf(-x1));
        num += g0 * b0 + g1 * b1;
        den += g0 + g1;
      }
      if (i < i1) {
        float x0 = __half2float(eh16[(size_t)i * 64 + c]);
        int s0 = srcp[i];
        float b0 = Bh[(size_t)s0 * 64 + c];
        float g0 = 1.0f / (1.0f + __expf(-x0));
        num += g0 * b0;
        den += g0;
      }
      float v = Ah[(size_t)n * 64 + c] + num / (den + 1e-6f);
      Ah[(size_t)n * 64 + c] = v;
      psum += v; psq += v * v;
    }
  }
  __shared__ float red[256];
  red[t] = psum; __syncthreads();
  if (t < 64) atomAddD(stats + t, (double)(red[t] + red[t + 64] + red[t + 128] + red[t + 192]));
  __syncthreads();
  red[t] = psq; __syncthreads();
  if (t < 64) atomAddD(stats + 64 + t, (double)(red[t] + red[t + 64] + red[t + 128] + red[t + 192]));
}

// ---------------- finalize BN scale/shift; zero stats for next layer ----------------
__global__ void k_bn_final(double* __restrict__ stats,
    const float* __restrict__ hgam, const float* __restrict__ hbet,
    const float* __restrict__ egam, const float* __restrict__ ebet,
    float* __restrict__ bnp) {
  int t = threadIdx.x;
  if (t < 64) {
    double mu = stats[t] * (1.0 / NN);
    double var = stats[64 + t] * (1.0 / NN) - mu * mu;
    float sc = hgam[t] / sqrtf((float)var + 1e-5f);
    bnp[t] = sc;
    bnp[64 + t] = hbet[t] - (float)mu * sc;
  } else if (t < 128) {
    int c = t - 64;
    double mu = stats[128 + c] * (1.0 / NE);
    double var = stats[192 + c] * (1.0 / NE) - mu * mu;
    float sc = egam[c] / sqrtf((float)var + 1e-5f);
    bnp[128 + c] = sc;
    bnp[192 + c] = ebet[c] - (float)mu * sc;
  }
  __syncthreads();
  stats[t] = 0.0;
  stats[t + 128] = 0.0;
}

// ---------------- readout with fused final h-residual ----------------
__global__ __launch_bounds__(256) void k_readout(const float* __restrict__ h,
    const float* __restrict__ Ah, const float* __restrict__ bnp,
    const int* __restrict__ gid, float* __restrict__ hg, float* __restrict__ counts) {
  int t = threadIdx.x;
  int c = t & 63;
  int ro = t >> 6;
  int nbase = blockIdx.x * 64;
  float sc = bnp[c], sh = bnp[64 + c];
  float sum = 0.f, cnt = 0.f;
  int curg = -1;
  #pragma unroll 1
  for (int i = 0; i < 16; ++i) {
    int n = nbase + ro + i * 4;
    if (n >= NN) break;
    int g = gid[n];
    if (g != curg) {
      if (curg >= 0) {
        atomAddF(&hg[curg * 64 + c], sum);
        if (c == 0) atomAddF(&counts[curg], cnt);
      }
      curg = g; sum = 0.f; cnt = 0.f;
    }
    size_t idx = (size_t)n * 64 + c;
    sum += h[idx] + fmaxf(Ah[idx] * sc + sh, 0.f);
    cnt += 1.f;
  }
  if (curg >= 0) {
    atomAddF(&hg[curg * 64 + c], sum);
    if (c == 0) atomAddF(&counts[curg], cnt);
  }
}

// ---------------- final MLP (16 graphs), one block ----------------
__global__ __launch_bounds__(256) void k_mlp(const float* __restrict__ hg, const float* __restrict__ counts,
    const float* __restrict__ state,
    const float* __restrict__ w1, const float* __restrict__ b1,
    const float* __restrict__ w2, const float* __restrict__ b2,
    const float* __restrict__ w3, const float* __restrict__ b3,
    float* __restrict__ out) {
  __shared__ float x0[16][68];
  __shared__ float x1[16][256];
  __shared__ float x2[16][256];
  int t = threadIdx.x;
  for (int idx = t; idx < 16 * 68; idx += 256) {
    int g = idx / 68, c = idx % 68;
    x0[g][c] = (c < 64) ? hg[g * 64 + c] / counts[g] : state[g * 4 + (c - 64)];
  }
  __syncthreads();
  {
    float acc[16];
    float bb = b1[t];
    #pragma unroll
    for (int g = 0; g < 16; ++g) acc[g] = bb;
    for (int k = 0; k < 68; ++k) {
      float w = w1[k * 256 + t];
      #pragma unroll
      for (int g = 0; g < 16; ++g) acc[g] += x0[g][k] * w;
    }
    #pragma unroll
    for (int g = 0; g < 16; ++g) x1[g][t] = fmaxf(acc[g], 0.f);
  }
  __syncthreads();
  {
    float acc[16];
    float bb = b2[t];
    #pragma unroll
    for (int g = 0; g < 16; ++g) acc[g] = bb;
    for (int k = 0; k < 256; ++k) {
      float w = w2[k * 256 + t];
      #pragma unroll
      for (int g = 0; g < 16; ++g) acc[g] += x1[g][k] * w;
    }
    #pragma unroll
    for (int g = 0; g < 16; ++g) x2[g][t] = fmaxf(acc[g], 0.f);
  }
  __syncthreads();
  if (t < 32) {
    int g = t >> 1, o = t & 1;
    float acc = b3[o];
    for (int k = 0; k < 256; ++k) acc += x2[g][k] * w3[k * 2 + o];
    out[g * 2 + o] = tanhf(acc);
  }
}

extern "C" void kernel_launch(void* const* d_in, const int* in_sizes, int n_in,
                              void* d_out, int out_size, void* d_ws, size_t ws_size,
                              hipStream_t stream) {
  const float* state   = (const float*)d_in[0];
  const float* h_feat  = (const float*)d_in[1];
  const float* e_feat  = (const float*)d_in[2];
  const int*   src     = (const int*)d_in[3];
  const int*   dst     = (const int*)d_in[4];
  const int*   gid     = (const int*)d_in[5];
  const float* emb_h_w = (const float*)d_in[6];
  const float* emb_h_b = (const float*)d_in[7];
  const float* emb_e_w = (const float*)d_in[8];
  const float* emb_e_b = (const float*)d_in[9];
  const float* A_w = (const float*)d_in[10];
  const float* A_b = (const float*)d_in[11];
  const float* B_w = (const float*)d_in[12];
  const float* B_b = (const float*)d_in[13];
  const float* C_w = (const float*)d_in[14];
  const float* C_b = (const float*)d_in[15];
  const float* D_w = (const float*)d_in[16];
  const float* D_b = (const float*)d_in[17];
  const float* E_w = (const float*)d_in[18];
  const float* E_b = (const float*)d_in[19];
  const float* bn_h_g = (const float*)d_in[20];
  const float* bn_h_b = (const float*)d_in[21];
  const float* bn_e_g = (const float*)d_in[22];
  const float* bn_e_b = (const float*)d_in[23];
  const float* l1_w = (const float*)d_in[24];
  const float* l1_b = (const float*)d_in[25];
  const float* l2_w = (const float*)d_in[26];
  const float* l2_b = (const float*)d_in[27];
  const float* l3_w = (const float*)d_in[28];
  const float* l3_b = (const float*)d_in[29];

  float* wsp = (float*)d_ws;

  const size_t F_H = (size_t)NN * 64;
  const size_t F_E = (size_t)NE * 64;
  size_t off = 0;
  float* h     = wsp + off; off += F_H;
  float* e     = wsp + off; off += F_E;
  float* Ah    = wsp + off; off += F_H;
  float* Bh    = wsp + off; off += F_H;
  float* Dh    = wsp + off; off += F_H;
  float* Eh    = wsp + off; off += F_H;
  __half* eh16 = (__half*)(wsp + off); off += F_E / 2;
  float* ef2   = (float*)eh16;  // overlay: raw CSR-ordered e_feat pairs (consumed before eh16 writes)
  int* srcp    = (int*)(wsp + off); off += NE;
  int* dstp    = (int*)(wsp + off); off += NE;
  int* offs    = (int*)(wsp + off); off += NN + 4;
  int* degcur  = (int*)(wsp + off); off += NN;
  double* stats = (double*)(wsp + off); off += 512;
  float* bnp    = wsp + off; off += 256;
  float* hg     = wsp + off; off += 1024;
  float* counts = hg + 1024; off += 16;
  const size_t need = off * sizeof(float);
  if (ws_size < need) return;

  // CSR build + embeds
  k_zero<<<64, 256, 0, stream>>>((float4*)degcur, NN / 4);
  k_deg<<<(NE + 255) / 256, 256, 0, stream>>>(dst, degcur);
  k_scan<<<1, 1024, 0, stream>>>(degcur, offs, stats);
  k_scatter<<<(NE + 255) / 256, 256, 0, stream>>>(dst, src, e_feat, degcur, srcp, dstp, ef2);
  k_embed_e<<<(NE * 16 + 255) / 256, 256, 0, stream>>>(ef2, emb_e_w, emb_e_b, e);
  k_embed_h<<<(NN * 16 + 255) / 256, 256, 0, stream>>>(h_feat, emb_h_w, emb_h_b, h);

  const int GN = (NN + 63) / 64;
  const int GE = NE / 64;
  for (int l = 0; l < 3; ++l) {
    if (l == 0)
      k_node_gemm<0><<<GN, 256, 0, stream>>>(h, Ah, bnp,
          A_w, B_w, D_w, E_w, A_b, B_b, D_b, E_b, Ah);
    else
      k_node_gemm<1><<<GN, 256, 0, stream>>>(h, Ah, bnp,
          A_w + l * 4096, B_w + l * 4096, D_w + l * 4096, E_w + l * 4096,
          A_b + l * 64, B_b + l * 64, D_b + l * 64, E_b + l * 64, Ah);
    if (l == 0)
      k_edge_f<0, 1, 0><<<GE, 256, 0, stream>>>(e, eh16, C_w, C_b,
          srcp, dstp, Dh, Eh, bnp, stats);
    else if (l == 1)
      k_edge_f<1, 1, 1><<<GE, 256, 0, stream>>>(e, eh16, C_w + 4096, C_b + 64,
          srcp, dstp, Dh, Eh, bnp, stats);
    else
      k_edge_f<1, 0, 0><<<GE, 256, 0, stream>>>(e, eh16, C_w + 8192, C_b + 128,
          srcp, dstp, Dh, Eh, bnp, stats);
    k_agg<<<(NN + 15) / 16, 256, 0, stream>>>(offs, srcp, eh16, Bh, Ah, stats);
    k_bn_final<<<1, 128, 0, stream>>>(stats, bn_h_g + l * 64, bn_h_b + l * 64,
        bn_e_g + l * 64, bn_e_b + l * 64, bnp);
  }
  k_zero<<<2, 256, 0, stream>>>((float4*)hg, (1024 + 16) / 4);
  k_readout<<<(NN + 63) / 64, 256, 0, stream>>>(h, Ah, bnp, gid, hg, counts);
  k_mlp<<<1, 256, 0, stream>>>(hg, counts, state,
      l1_w, l1_b, l2_w, l2_b, l3_w, l3_b, (float*)d_out);
}

// Round 8
// 925.368 us; speedup vs baseline: 2.5124x; 1.1908x over previous
//
#include <hip/hip_runtime.h>
#include <hip/hip_fp16.h>
#include <math.h>
#include <string.h>

#define NN 50000
#define NE 400000

// XOR swizzle group: bits 2-4 of k (k/4 mod 8) << 2. Bijective on row ^ SK within 128 rows.
#define SK(k) ((((k) >> 2) & 7) << 2)

__device__ __forceinline__ void atomAddF(float* p, float v) { unsafeAtomicAdd(p, v); }
__device__ __forceinline__ void atomAddD(double* p, double v) { unsafeAtomicAdd(p, v); }
__device__ __forceinline__ int atomAddI(int* p, int v) { return atomicAdd(p, v); }

__device__ __forceinline__ float2 up2h(unsigned v) {
  __half2 h; memcpy(&h, &v, 4); return __half22float2(h);
}
__device__ __forceinline__ unsigned pk2h(float a, float b) {
  __half2 h = __floats2half2_rn(a, b);
  unsigned v; memcpy(&v, &h, 4); return v;
}

// ---------------- zero fill ----------------
__global__ __launch_bounds__(256) void k_zero(float4* __restrict__ p, int n4) {
  int i = blockIdx.x * 256 + threadIdx.x;
  int s = gridDim.x * 256;
  for (; i < n4; i += s) p[i] = make_float4(0.f, 0.f, 0.f, 0.f);
}

// ---------------- embeddings ----------------
__global__ __launch_bounds__(256) void k_embed_h(const float* __restrict__ hf,
    const float* __restrict__ w, const float* __restrict__ b, float* __restrict__ h) {
  int i = blockIdx.x * 256 + threadIdx.x;
  if (i >= NN * 16) return;
  int n = i >> 4, c0 = (i & 15) * 4;
  float4 acc = *(const float4*)(b + c0);
  const float* row = hf + n * 6;
  #pragma unroll
  for (int k = 0; k < 6; ++k) {
    float x = row[k];
    const float4 wv = *(const float4*)(w + k * 64 + c0);
    acc.x += x * wv.x; acc.y += x * wv.y; acc.z += x * wv.z; acc.w += x * wv.w;
  }
  ((float4*)h)[i] = acc;
}

__global__ __launch_bounds__(256) void k_embed_e(const float* __restrict__ ef2,
    const float* __restrict__ w, const float* __restrict__ b, float* __restrict__ e) {
  int i = blockIdx.x * 256 + threadIdx.x;
  if (i >= NE * 16) return;
  int p = i >> 4, c0 = (i & 15) * 4;
  float2 raw = ((const float2*)ef2)[p];
  float r0 = 1.0f / raw.x;
  float r1 = 1.0f / raw.y;
  float4 acc = *(const float4*)(b + c0);
  const float4 w0 = *(const float4*)(w + c0);
  const float4 w1 = *(const float4*)(w + 64 + c0);
  acc.x += r0 * w0.x + r1 * w1.x;
  acc.y += r0 * w0.y + r1 * w1.y;
  acc.z += r0 * w0.z + r1 * w1.z;
  acc.w += r0 * w0.w + r1 * w1.w;
  ((float4*)e)[i] = acc;
}

// ---------------- CSR build ----------------
__global__ __launch_bounds__(256) void k_deg(const int* __restrict__ dst, int* __restrict__ deg) {
  int i = blockIdx.x * 256 + threadIdx.x;
  if (i < NE) atomAddI(&deg[dst[i]], 1);
}

__global__ __launch_bounds__(1024) void k_scan(int* __restrict__ degcur,
    int* __restrict__ offs, double* __restrict__ stats) {
  __shared__ int wsum[16];
  int t = threadIdx.x;
  int lane = t & 63, w = t >> 6;
  if (t < 256) stats[t] = 0.0;
  int carry = 0;
  for (int base = 0; base < NN; base += 1024) {
    int i = base + t;
    int v = (i < NN) ? degcur[i] : 0;
    int x = v;
    #pragma unroll
    for (int off = 1; off < 64; off <<= 1) {
      int y = __shfl_up(x, off);
      if (lane >= off) x += y;
    }
    if (lane == 63) wsum[w] = x;
    __syncthreads();
    if (w == 0 && lane < 16) {
      int s = wsum[lane];
      #pragma unroll
      for (int off = 1; off < 16; off <<= 1) {
        int y = __shfl_up(s, off);
        if (lane >= off) s += y;
      }
      wsum[lane] = s;
    }
    __syncthreads();
    int wbase = (w > 0) ? wsum[w - 1] : 0;
    int total = wsum[15];
    int excl = carry + wbase + x - v;
    if (i < NN) { offs[i] = excl; degcur[i] = excl; }
    carry += total;
    __syncthreads();
  }
  if (t == 0) offs[NN] = carry;
}

__global__ __launch_bounds__(256) void k_scatter(const int* __restrict__ dst,
    const int* __restrict__ src, const float* __restrict__ e_feat,
    int* __restrict__ cursor,
    int* __restrict__ srcp, int* __restrict__ dstp, float* __restrict__ ef2) {
  int i = blockIdx.x * 256 + threadIdx.x;
  if (i < NE) {
    int d = dst[i];
    int p = atomAddI(&cursor[d], 1);
    srcp[p] = src[i];
    dstp[p] = d;
    ((float2*)ef2)[p] = ((const float2*)e_feat)[i];
  }
}

// ---------------- node GEMM, 128-row tile, XOR-swizzled LDS (48KB -> 3 blk/CU) ---------
// MODE==1: during staging, h_new = h + relu(Ah*sc + sh); write h back; GEMM uses h_new.
template <int MODE>
__global__ __launch_bounds__(256) void k_node_gemm(float* __restrict__ h,
    const float* __restrict__ Ah_in, const float* __restrict__ bnp,
    const float* __restrict__ w0, const float* __restrict__ w1,
    const float* __restrict__ w2, const float* __restrict__ w3,
    const float* __restrict__ b0, const float* __restrict__ b1,
    const float* __restrict__ b2, const float* __restrict__ b3,
    float* __restrict__ out) {
  __shared__ float hsT[64 * 128];   // [k][row ^ SK(k)]
  __shared__ float wsh[64 * 64];
  int t = threadIdx.x;
  int n0 = blockIdx.x * 128;
  #pragma unroll
  for (int i = 0; i < 8; ++i) {
    int f = (t + i * 256) * 4;
    int r = f >> 6;          // 0..127
    int k = f & 63;          // multiple of 4
    int n = n0 + r;
    float4 v = make_float4(0.f, 0.f, 0.f, 0.f);
    if (n < NN) {
      size_t idx = (size_t)n * 64 + k;
      v = *(const float4*)(h + idx);
      if (MODE == 1) {
        float4 av = *(const float4*)(Ah_in + idx);
        float4 sc4 = *(const float4*)(bnp + k);
        float4 sh4 = *(const float4*)(bnp + 64 + k);
        v.x += fmaxf(av.x * sc4.x + sh4.x, 0.f);
        v.y += fmaxf(av.y * sc4.y + sh4.y, 0.f);
        v.z += fmaxf(av.z * sc4.z + sh4.z, 0.f);
        v.w += fmaxf(av.w * sc4.w + sh4.w, 0.f);
        *(float4*)(h + idx) = v;
      }
    }
    int rs = r ^ SK(k);      // same group for k..k+3
    hsT[(k + 0) * 128 + rs] = v.x;
    hsT[(k + 1) * 128 + rs] = v.y;
    hsT[(k + 2) * 128 + rs] = v.z;
    hsT[(k + 3) * 128 + rs] = v.w;
  }
  int cg = t & 7, rg = t >> 3;   // rg 0..31 (4 rows each), cg 0..7 (8 cols)
  int cb = cg * 8;
  #pragma unroll 1
  for (int y = 0; y < 4; ++y) {
    const float* W = (y == 0) ? w0 : (y == 1) ? w1 : (y == 2) ? w2 : w3;
    const float* B = (y == 0) ? b0 : (y == 1) ? b1 : (y == 2) ? b2 : b3;
    __syncthreads();
    #pragma unroll
    for (int i = 0; i < 4; ++i)
      ((float4*)wsh)[t + i * 256] = ((const float4*)W)[t + i * 256];
    __syncthreads();
    float acc[4][8];
    #pragma unroll
    for (int r = 0; r < 4; ++r)
      #pragma unroll
      for (int j = 0; j < 8; ++j) acc[r][j] = 0.f;
    #pragma unroll 8
    for (int k = 0; k < 64; ++k) {
      float4 av = *(const float4*)&hsT[k * 128 + ((rg * 4) ^ SK(k))];
      float4 wv0 = *(const float4*)&wsh[k * 64 + cb];
      float4 wv1 = *(const float4*)&wsh[k * 64 + cb + 4];
      float a[4] = {av.x, av.y, av.z, av.w};
      float w[8] = {wv0.x, wv0.y, wv0.z, wv0.w, wv1.x, wv1.y, wv1.z, wv1.w};
      #pragma unroll
      for (int r = 0; r < 4; ++r)
        #pragma unroll
        for (int j = 0; j < 8; ++j) acc[r][j] += a[r] * w[j];
    }
    float4 bv0 = *(const float4*)(B + cb);
    float4 bv1 = *(const float4*)(B + cb + 4);
    float* oy = out + (size_t)y * NN * 64;
    #pragma unroll
    for (int r = 0; r < 4; ++r) {
      int n = n0 + rg * 4 + r;
      if (n < NN) {
        *(float4*)(oy + (size_t)n * 64 + cb) =
            make_float4(acc[r][0] + bv0.x, acc[r][1] + bv0.y,
                        acc[r][2] + bv0.z, acc[r][3] + bv0.w);
        *(float4*)(oy + (size_t)n * 64 + cb + 4) =
            make_float4(acc[r][4] + bv1.x, acc[r][5] + bv1.y,
                        acc[r][6] + bv1.z, acc[r][7] + bv1.w);
      }
    }
  }
}

// ---------------- fused edge kernel, 128-row tile, XOR-swizzled LDS ----------------
// MODE==1: e_new = e + relu(eh16_prev*sc+sh) during staging; EWRITE: write e back.
// ehat = e_new@Cw + Cb + Dh[srcp] + Eh[dstp]; store fp16; ESTATS: e-BN stats.
template <int MODE, int ESTATS, int EWRITE>
__global__ __launch_bounds__(256) void k_edge_f(float* __restrict__ e,
    __half* __restrict__ eh16,
    const float* __restrict__ Cw, const float* __restrict__ Cb,
    const int* __restrict__ srcp, const int* __restrict__ dstp,
    const float* __restrict__ Dh, const float* __restrict__ Eh,
    const float* __restrict__ bnp, double* __restrict__ stats) {
  __shared__ float esT[64 * 128];   // [k][row ^ SK(k)]
  __shared__ float cw[64 * 64];
  int t = threadIdx.x;
  int e0 = blockIdx.x * 128;
  #pragma unroll
  for (int i = 0; i < 4; ++i)
    ((float4*)cw)[t + i * 256] = ((const float4*)Cw)[t + i * 256];
  #pragma unroll
  for (int i = 0; i < 8; ++i) {
    int f = (t + i * 256) * 4;
    int r = f >> 6;
    int k = f & 63;
    size_t idx = (size_t)(e0 + r) * 64 + k;
    float4 v = *(const float4*)(e + idx);
    if (MODE == 1) {
      uint2 hh = *(const uint2*)(eh16 + idx);
      float2 fa = up2h(hh.x), fb = up2h(hh.y);
      float4 sc4 = *(const float4*)(bnp + 128 + k);
      float4 sh4 = *(const float4*)(bnp + 192 + k);
      v.x += fmaxf(fa.x * sc4.x + sh4.x, 0.f);
      v.y += fmaxf(fa.y * sc4.y + sh4.y, 0.f);
      v.z += fmaxf(fb.x * sc4.z + sh4.z, 0.f);
      v.w += fmaxf(fb.y * sc4.w + sh4.w, 0.f);
      if (EWRITE) *(float4*)(e + idx) = v;
    }
    int rs = r ^ SK(k);
    esT[(k + 0) * 128 + rs] = v.x;
    esT[(k + 1) * 128 + rs] = v.y;
    esT[(k + 2) * 128 + rs] = v.z;
    esT[(k + 3) * 128 + rs] = v.w;
  }
  __syncthreads();
  int cg = t & 7, rg = t >> 3;
  int cb = cg * 8;
  float acc[4][8];
  #pragma unroll
  for (int r = 0; r < 4; ++r)
    #pragma unroll
    for (int j = 0; j < 8; ++j) acc[r][j] = 0.f;
  #pragma unroll 8
  for (int k = 0; k < 64; ++k) {
    float4 av = *(const float4*)&esT[k * 128 + ((rg * 4) ^ SK(k))];
    float4 wv0 = *(const float4*)&cw[k * 64 + cb];
    float4 wv1 = *(const float4*)&cw[k * 64 + cb + 4];
    float a[4] = {av.x, av.y, av.z, av.w};
    float w[8] = {wv0.x, wv0.y, wv0.z, wv0.w, wv1.x, wv1.y, wv1.z, wv1.w};
    #pragma unroll
    for (int r = 0; r < 4; ++r)
      #pragma unroll
      for (int j = 0; j < 8; ++j) acc[r][j] += a[r] * w[j];
  }
  float4 cb0 = *(const float4*)(Cb + cb);
  float4 cb1 = *(const float4*)(Cb + cb + 4);
  float cbv[8] = {cb0.x, cb0.y, cb0.z, cb0.w, cb1.x, cb1.y, cb1.z, cb1.w};
  float psum[8], psq[8];
  #pragma unroll
  for (int j = 0; j < 8; ++j) { psum[j] = 0.f; psq[j] = 0.f; }
  #pragma unroll
  for (int r = 0; r < 4; ++r) {
    int p = e0 + rg * 4 + r;
    int sN = srcp[p], dN = dstp[p];
    const float* dp = Dh + (size_t)sN * 64 + cb;
    const float* ep = Eh + (size_t)dN * 64 + cb;
    float4 d0 = *(const float4*)dp, d1 = *(const float4*)(dp + 4);
    float4 q0 = *(const float4*)ep, q1 = *(const float4*)(ep + 4);
    float dd[8] = {d0.x, d0.y, d0.z, d0.w, d1.x, d1.y, d1.z, d1.w};
    float qq[8] = {q0.x, q0.y, q0.z, q0.w, q1.x, q1.y, q1.z, q1.w};
    float ev[8];
    #pragma unroll
    for (int j = 0; j < 8; ++j) {
      float v = acc[r][j] + cbv[j] + dd[j] + qq[j];
      ev[j] = v;
      if (ESTATS) { psum[j] += v; psq[j] += v * v; }
    }
    uint4 u;
    u.x = pk2h(ev[0], ev[1]);
    u.y = pk2h(ev[2], ev[3]);
    u.z = pk2h(ev[4], ev[5]);
    u.w = pk2h(ev[6], ev[7]);
    *(uint4*)(eh16 + (size_t)p * 64 + cb) = u;
  }
  if (ESTATS) {
    __syncthreads();  // esT reuse for stats reduce
    #pragma unroll
    for (int j = 0; j < 8; ++j) {
      esT[rg * 65 + cb + j] = psum[j];
      esT[2304 + rg * 65 + cb + j] = psq[j];
    }
    __syncthreads();
    if (t < 64) {
      float s = 0.f, q = 0.f;
      #pragma unroll
      for (int i = 0; i < 32; ++i) { s += esT[i * 65 + t]; q += esT[2304 + i * 65 + t]; }
      atomAddD(stats + 128 + t, (double)s);
      atomAddD(stats + 192 + t, (double)q);
    }
  }
}

// ---------------- aggregation (16 nodes/block, 4 sequential per thread) ----------------
__global__ __launch_bounds__(256) void k_agg(const int* __restrict__ offs,
    const int* __restrict__ srcp, const __half* __restrict__ eh16,
    const float* __restrict__ Bh, float* __restrict__ Ah, double* __restrict__ stats) {
  int t = threadIdx.x;
  int c = t & 63;
  int g = t >> 6;
  float psum = 0.f, psq = 0.f;
  #pragma unroll 1
  for (int sub = 0; sub < 4; ++sub) {
    int n = blockIdx.x * 16 + g * 4 + sub;
    if (n < NN) {
      int i0 = offs[n], i1 = offs[n + 1];
      float num = 0.f, den = 0.f;
      int i = i0;
      #pragma unroll 1
      for (; i + 1 < i1; i += 2) {
        float x0 = __half2float(eh16[(size_t)i * 64 + c]);
        float x1 = __half2float(eh16[(size_t)(i + 1) * 64 + c]);
        int s0 = srcp[i], s1 = srcp[i + 1];
        float b0 = Bh[(size_t)s0 * 64 + c];
        float b1 = Bh[(size_t)s1 * 64 + c];
        float g0 = 1.0f / (1.0f + __expf(-x0));
        float g1 = 1.0f / (1.0f + __expf(-x1));
        num += g0 * b0 + g1 * b1;
        den += g0 + g1;
      }
      if (i < i1) {
        float x0 = __half2float(eh16[(size_t)i * 64 + c]);
        int s0 = srcp[i];
        float b0 = Bh[(size_t)s0 * 64 + c];
        float g0 = 1.0f / (1.0f + __expf(-x0));
        num += g0 * b0;
        den += g0;
      }
      float v = Ah[(size_t)n * 64 + c] + num / (den + 1e-6f);
      Ah[(size_t)n * 64 + c] = v;
      psum += v; psq += v * v;
    }
  }
  __shared__ float red[256];
  red[t] = psum; __syncthreads();
  if (t < 64) atomAddD(stats + t, (double)(red[t] + red[t + 64] + red[t + 128] + red[t + 192]));
  __syncthreads();
  red[t] = psq; __syncthreads();
  if (t < 64) atomAddD(stats + 64 + t, (double)(red[t] + red[t + 64] + red[t + 128] + red[t + 192]));
}

// ---------------- finalize BN scale/shift; zero stats for next layer ----------------
__global__ void k_bn_final(double* __restrict__ stats,
    const float* __restrict__ hgam, const float* __restrict__ hbet,
    const float* __restrict__ egam, const float* __restrict__ ebet,
    float* __restrict__ bnp) {
  int t = threadIdx.x;
  if (t < 64) {
    double mu = stats[t] * (1.0 / NN);
    double var = stats[64 + t] * (1.0 / NN) - mu * mu;
    float sc = hgam[t] / sqrtf((float)var + 1e-5f);
    bnp[t] = sc;
    bnp[64 + t] = hbet[t] - (float)mu * sc;
  } else if (t < 128) {
    int c = t - 64;
    double mu = stats[128 + c] * (1.0 / NE);
    double var = stats[192 + c] * (1.0 / NE) - mu * mu;
    float sc = egam[c] / sqrtf((float)var + 1e-5f);
    bnp[128 + c] = sc;
    bnp[192 + c] = ebet[c] - (float)mu * sc;
  }
  __syncthreads();
  stats[t] = 0.0;
  stats[t + 128] = 0.0;
}

// ---------------- readout with fused final h-residual ----------------
__global__ __launch_bounds__(256) void k_readout(const float* __restrict__ h,
    const float* __restrict__ Ah, const float* __restrict__ bnp,
    const int* __restrict__ gid, float* __restrict__ hg, float* __restrict__ counts) {
  int t = threadIdx.x;
  int c = t & 63;
  int ro = t >> 6;
  int nbase = blockIdx.x * 64;
  float sc = bnp[c], sh = bnp[64 + c];
  float sum = 0.f, cnt = 0.f;
  int curg = -1;
  #pragma unroll 1
  for (int i = 0; i < 16; ++i) {
    int n = nbase + ro + i * 4;
    if (n >= NN) break;
    int g = gid[n];
    if (g != curg) {
      if (curg >= 0) {
        atomAddF(&hg[curg * 64 + c], sum);
        if (c == 0) atomAddF(&counts[curg], cnt);
      }
      curg = g; sum = 0.f; cnt = 0.f;
    }
    size_t idx = (size_t)n * 64 + c;
    sum += h[idx] + fmaxf(Ah[idx] * sc + sh, 0.f);
    cnt += 1.f;
  }
  if (curg >= 0) {
    atomAddF(&hg[curg * 64 + c], sum);
    if (c == 0) atomAddF(&counts[curg], cnt);
  }
}

// ---------------- final MLP (16 graphs), one block ----------------
__global__ __launch_bounds__(256) void k_mlp(const float* __restrict__ hg, const float* __restrict__ counts,
    const float* __restrict__ state,
    const float* __restrict__ w1, const float* __restrict__ b1,
    const float* __restrict__ w2, const float* __restrict__ b2,
    const float* __restrict__ w3, const float* __restrict__ b3,
    float* __restrict__ out) {
  __shared__ float x0[16][68];
  __shared__ float x1[16][256];
  __shared__ float x2[16][256];
  int t = threadIdx.x;
  for (int idx = t; idx < 16 * 68; idx += 256) {
    int g = idx / 68, c = idx % 68;
    x0[g][c] = (c < 64) ? hg[g * 64 + c] / counts[g] : state[g * 4 + (c - 64)];
  }
  __syncthreads();
  {
    float acc[16];
    float bb = b1[t];
    #pragma unroll
    for (int g = 0; g < 16; ++g) acc[g] = bb;
    for (int k = 0; k < 68; ++k) {
      float w = w1[k * 256 + t];
      #pragma unroll
      for (int g = 0; g < 16; ++g) acc[g] += x0[g][k] * w;
    }
    #pragma unroll
    for (int g = 0; g < 16; ++g) x1[g][t] = fmaxf(acc[g], 0.f);
  }
  __syncthreads();
  {
    float acc[16];
    float bb = b2[t];
    #pragma unroll
    for (int g = 0; g < 16; ++g) acc[g] = bb;
    for (int k = 0; k < 256; ++k) {
      float w = w2[k * 256 + t];
      #pragma unroll
      for (int g = 0; g < 16; ++g) acc[g] += x1[g][k] * w;
    }
    #pragma unroll
    for (int g = 0; g < 16; ++g) x2[g][t] = fmaxf(acc[g], 0.f);
  }
  __syncthreads();
  if (t < 32) {
    int g = t >> 1, o = t & 1;
    float acc = b3[o];
    for (int k = 0; k < 256; ++k) acc += x2[g][k] * w3[k * 2 + o];
    out[g * 2 + o] = tanhf(acc);
  }
}

extern "C" void kernel_launch(void* const* d_in, const int* in_sizes, int n_in,
                              void* d_out, int out_size, void* d_ws, size_t ws_size,
                              hipStream_t stream) {
  const float* state   = (const float*)d_in[0];
  const float* h_feat  = (const float*)d_in[1];
  const float* e_feat  = (const float*)d_in[2];
  const int*   src     = (const int*)d_in[3];
  const int*   dst     = (const int*)d_in[4];
  const int*   gid     = (const int*)d_in[5];
  const float* emb_h_w = (const float*)d_in[6];
  const float* emb_h_b = (const float*)d_in[7];
  const float* emb_e_w = (const float*)d_in[8];
  const float* emb_e_b = (const float*)d_in[9];
  const float* A_w = (const float*)d_in[10];
  const float* A_b = (const float*)d_in[11];
  const float* B_w = (const float*)d_in[12];
  const float* B_b = (const float*)d_in[13];
  const float* C_w = (const float*)d_in[14];
  const float* C_b = (const float*)d_in[15];
  const float* D_w = (const float*)d_in[16];
  const float* D_b = (const float*)d_in[17];
  const float* E_w = (const float*)d_in[18];
  const float* E_b = (const float*)d_in[19];
  const float* bn_h_g = (const float*)d_in[20];
  const float* bn_h_b = (const float*)d_in[21];
  const float* bn_e_g = (const float*)d_in[22];
  const float* bn_e_b = (const float*)d_in[23];
  const float* l1_w = (const float*)d_in[24];
  const float* l1_b = (const float*)d_in[25];
  const float* l2_w = (const float*)d_in[26];
  const float* l2_b = (const float*)d_in[27];
  const float* l3_w = (const float*)d_in[28];
  const float* l3_b = (const float*)d_in[29];

  float* wsp = (float*)d_ws;

  const size_t F_H = (size_t)NN * 64;
  const size_t F_E = (size_t)NE * 64;
  size_t off = 0;
  float* h     = wsp + off; off += F_H;
  float* e     = wsp + off; off += F_E;
  float* Ah    = wsp + off; off += F_H;
  float* Bh    = wsp + off; off += F_H;
  float* Dh    = wsp + off; off += F_H;
  float* Eh    = wsp + off; off += F_H;
  __half* eh16 = (__half*)(wsp + off); off += F_E / 2;
  float* ef2   = (float*)eh16;  // overlay: raw CSR-ordered e_feat pairs (consumed before eh16 writes)
  int* srcp    = (int*)(wsp + off); off += NE;
  int* dstp    = (int*)(wsp + off); off += NE;
  int* offs    = (int*)(wsp + off); off += NN + 4;
  int* degcur  = (int*)(wsp + off); off += NN;
  double* stats = (double*)(wsp + off); off += 512;
  float* bnp    = wsp + off; off += 256;
  float* hg     = wsp + off; off += 1024;
  float* counts = hg + 1024; off += 16;
  const size_t need = off * sizeof(float);
  if (ws_size < need) return;

  // CSR build + embeds
  k_zero<<<64, 256, 0, stream>>>((float4*)degcur, NN / 4);
  k_deg<<<(NE + 255) / 256, 256, 0, stream>>>(dst, degcur);
  k_scan<<<1, 1024, 0, stream>>>(degcur, offs, stats);
  k_scatter<<<(NE + 255) / 256, 256, 0, stream>>>(dst, src, e_feat, degcur, srcp, dstp, ef2);
  k_embed_e<<<(NE * 16 + 255) / 256, 256, 0, stream>>>(ef2, emb_e_w, emb_e_b, e);
  k_embed_h<<<(NN * 16 + 255) / 256, 256, 0, stream>>>(h_feat, emb_h_w, emb_h_b, h);

  const int GN = (NN + 127) / 128;
  const int GE = NE / 128;
  for (int l = 0; l < 3; ++l) {
    if (l == 0)
      k_node_gemm<0><<<GN, 256, 0, stream>>>(h, Ah, bnp,
          A_w, B_w, D_w, E_w, A_b, B_b, D_b, E_b, Ah);
    else
      k_node_gemm<1><<<GN, 256, 0, stream>>>(h, Ah, bnp,
          A_w + l * 4096, B_w + l * 4096, D_w + l * 4096, E_w + l * 4096,
          A_b + l * 64, B_b + l * 64, D_b + l * 64, E_b + l * 64, Ah);
    if (l == 0)
      k_edge_f<0, 1, 0><<<GE, 256, 0, stream>>>(e, eh16, C_w, C_b,
          srcp, dstp, Dh, Eh, bnp, stats);
    else if (l == 1)
      k_edge_f<1, 1, 1><<<GE, 256, 0, stream>>>(e, eh16, C_w + 4096, C_b + 64,
          srcp, dstp, Dh, Eh, bnp, stats);
    else
      k_edge_f<1, 0, 0><<<GE, 256, 0, stream>>>(e, eh16, C_w + 8192, C_b + 128,
          srcp, dstp, Dh, Eh, bnp, stats);
    k_agg<<<(NN + 15) / 16, 256, 0, stream>>>(offs, srcp, eh16, Bh, Ah, stats);
    k_bn_final<<<1, 128, 0, stream>>>(stats, bn_h_g + l * 64, bn_h_b + l * 64,
        bn_e_g + l * 64, bn_e_b + l * 64, bnp);
  }
  k_zero<<<2, 256, 0, stream>>>((float4*)hg, (1024 + 16) / 4);
  k_readout<<<(NN + 63) / 64, 256, 0, stream>>>(h, Ah, bnp, gid, hg, counts);
  k_mlp<<<1, 256, 0, stream>>>(hg, counts, state,
      l1_w, l1_b, l2_w, l2_b, l3_w, l3_b, (float*)d_out);
}

// Round 9
// 890.821 us; speedup vs baseline: 2.6098x; 1.0388x over previous
//
#include <hip/hip_runtime.h>
#include <hip/hip_fp16.h>
#include <math.h>
#include <string.h>

#define NN 50000
#define NE 400000

// XOR swizzle group: bits 2-4 of k (k/4 mod 8) << 2. Bijective on row ^ SK within 128 rows.
#define SK(k) ((((k) >> 2) & 7) << 2)

__device__ __forceinline__ void atomAddF(float* p, float v) { unsafeAtomicAdd(p, v); }
__device__ __forceinline__ void atomAddD(double* p, double v) { unsafeAtomicAdd(p, v); }
__device__ __forceinline__ int atomAddI(int* p, int v) { return atomicAdd(p, v); }

__device__ __forceinline__ float2 up2h(unsigned v) {
  __half2 h; memcpy(&h, &v, 4); return __half22float2(h);
}
__device__ __forceinline__ unsigned pk2h(float a, float b) {
  __half2 h = __floats2half2_rn(a, b);
  unsigned v; memcpy(&v, &h, 4); return v;
}
__device__ __forceinline__ void up8(uint4 u, float* f) {
  float2 a = up2h(u.x), b = up2h(u.y), c = up2h(u.z), d = up2h(u.w);
  f[0] = a.x; f[1] = a.y; f[2] = b.x; f[3] = b.y;
  f[4] = c.x; f[5] = c.y; f[6] = d.x; f[7] = d.y;
}
__device__ __forceinline__ uint4 pk8(const float* f) {
  uint4 u;
  u.x = pk2h(f[0], f[1]); u.y = pk2h(f[2], f[3]);
  u.z = pk2h(f[4], f[5]); u.w = pk2h(f[6], f[7]);
  return u;
}

// ---------------- zero fill ----------------
__global__ __launch_bounds__(256) void k_zero(float4* __restrict__ p, int n4) {
  int i = blockIdx.x * 256 + threadIdx.x;
  int s = gridDim.x * 256;
  for (; i < n4; i += s) p[i] = make_float4(0.f, 0.f, 0.f, 0.f);
}

// ---------------- embeddings ----------------
__global__ __launch_bounds__(256) void k_embed_h(const float* __restrict__ hf,
    const float* __restrict__ w, const float* __restrict__ b, float* __restrict__ h) {
  int i = blockIdx.x * 256 + threadIdx.x;
  if (i >= NN * 16) return;
  int n = i >> 4, c0 = (i & 15) * 4;
  float4 acc = *(const float4*)(b + c0);
  const float* row = hf + n * 6;
  #pragma unroll
  for (int k = 0; k < 6; ++k) {
    float x = row[k];
    const float4 wv = *(const float4*)(w + k * 64 + c0);
    acc.x += x * wv.x; acc.y += x * wv.y; acc.z += x * wv.z; acc.w += x * wv.w;
  }
  ((float4*)h)[i] = acc;
}

// e16 (fp16) in CSR order from raw pairs ef2 (already CSR-permuted)
__global__ __launch_bounds__(256) void k_embed_e(const float* __restrict__ ef2,
    const float* __restrict__ w, const float* __restrict__ b, __half* __restrict__ e16) {
  int i = blockIdx.x * 256 + threadIdx.x;
  if (i >= NE * 8) return;
  int p = i >> 3, c0 = (i & 7) * 8;
  float2 raw = ((const float2*)ef2)[p];
  float r0 = 1.0f / raw.x;
  float r1 = 1.0f / raw.y;
  float4 b0 = *(const float4*)(b + c0), b1 = *(const float4*)(b + c0 + 4);
  float4 wa0 = *(const float4*)(w + c0), wa1 = *(const float4*)(w + c0 + 4);
  float4 wb0 = *(const float4*)(w + 64 + c0), wb1 = *(const float4*)(w + 64 + c0 + 4);
  float o[8];
  o[0] = b0.x + r0 * wa0.x + r1 * wb0.x;
  o[1] = b0.y + r0 * wa0.y + r1 * wb0.y;
  o[2] = b0.z + r0 * wa0.z + r1 * wb0.z;
  o[3] = b0.w + r0 * wa0.w + r1 * wb0.w;
  o[4] = b1.x + r0 * wa1.x + r1 * wb1.x;
  o[5] = b1.y + r0 * wa1.y + r1 * wb1.y;
  o[6] = b1.z + r0 * wa1.z + r1 * wb1.z;
  o[7] = b1.w + r0 * wa1.w + r1 * wb1.w;
  *(uint4*)(e16 + (size_t)p * 64 + c0) = pk8(o);
}

// ---------------- CSR build ----------------
__global__ __launch_bounds__(256) void k_deg(const int* __restrict__ dst, int* __restrict__ deg) {
  int i = blockIdx.x * 256 + threadIdx.x;
  if (i < NE) atomAddI(&deg[dst[i]], 1);
}

__global__ __launch_bounds__(1024) void k_scan(int* __restrict__ degcur,
    int* __restrict__ offs, double* __restrict__ stats) {
  __shared__ int wsum[16];
  int t = threadIdx.x;
  int lane = t & 63, w = t >> 6;
  if (t < 256) stats[t] = 0.0;
  int carry = 0;
  for (int base = 0; base < NN; base += 1024) {
    int i = base + t;
    int v = (i < NN) ? degcur[i] : 0;
    int x = v;
    #pragma unroll
    for (int off = 1; off < 64; off <<= 1) {
      int y = __shfl_up(x, off);
      if (lane >= off) x += y;
    }
    if (lane == 63) wsum[w] = x;
    __syncthreads();
    if (w == 0 && lane < 16) {
      int s = wsum[lane];
      #pragma unroll
      for (int off = 1; off < 16; off <<= 1) {
        int y = __shfl_up(s, off);
        if (lane >= off) s += y;
      }
      wsum[lane] = s;
    }
    __syncthreads();
    int wbase = (w > 0) ? wsum[w - 1] : 0;
    int total = wsum[15];
    int excl = carry + wbase + x - v;
    if (i < NN) { offs[i] = excl; degcur[i] = excl; }
    carry += total;
    __syncthreads();
  }
  if (t == 0) offs[NN] = carry;
}

__global__ __launch_bounds__(256) void k_scatter(const int* __restrict__ dst,
    const int* __restrict__ src, const float* __restrict__ e_feat,
    int* __restrict__ cursor,
    int* __restrict__ srcp, int* __restrict__ dstp, float* __restrict__ ef2) {
  int i = blockIdx.x * 256 + threadIdx.x;
  if (i < NE) {
    int d = dst[i];
    int p = atomAddI(&cursor[d], 1);
    srcp[p] = src[i];
    dstp[p] = d;
    ((float2*)ef2)[p] = ((const float2*)e_feat)[i];
  }
}

// ---------------- node GEMM, 128-row tile, XOR-swizzled LDS ----------------
// MODE==1: during staging, h_new = h + relu(Ah*sc + sh); write h back; GEMM uses h_new.
// Outputs: Ah fp32, Bh/Dh/Eh fp16.
template <int MODE>
__global__ __launch_bounds__(256) void k_node_gemm(float* __restrict__ h,
    const float* __restrict__ Ah_in, const float* __restrict__ bnp,
    const float* __restrict__ w0, const float* __restrict__ w1,
    const float* __restrict__ w2, const float* __restrict__ w3,
    const float* __restrict__ b0, const float* __restrict__ b1,
    const float* __restrict__ b2, const float* __restrict__ b3,
    float* __restrict__ Ah, __half* __restrict__ Bh16,
    __half* __restrict__ Dh16, __half* __restrict__ Eh16) {
  __shared__ float hsT[64 * 128];   // [k][row ^ SK(k)]
  __shared__ float wsh[64 * 64];
  int t = threadIdx.x;
  int n0 = blockIdx.x * 128;
  #pragma unroll
  for (int i = 0; i < 8; ++i) {
    int f = (t + i * 256) * 4;
    int r = f >> 6;          // 0..127
    int k = f & 63;          // multiple of 4
    int n = n0 + r;
    float4 v = make_float4(0.f, 0.f, 0.f, 0.f);
    if (n < NN) {
      size_t idx = (size_t)n * 64 + k;
      v = *(const float4*)(h + idx);
      if (MODE == 1) {
        float4 av = *(const float4*)(Ah_in + idx);
        float4 sc4 = *(const float4*)(bnp + k);
        float4 sh4 = *(const float4*)(bnp + 64 + k);
        v.x += fmaxf(av.x * sc4.x + sh4.x, 0.f);
        v.y += fmaxf(av.y * sc4.y + sh4.y, 0.f);
        v.z += fmaxf(av.z * sc4.z + sh4.z, 0.f);
        v.w += fmaxf(av.w * sc4.w + sh4.w, 0.f);
        *(float4*)(h + idx) = v;
      }
    }
    int rs = r ^ SK(k);
    hsT[(k + 0) * 128 + rs] = v.x;
    hsT[(k + 1) * 128 + rs] = v.y;
    hsT[(k + 2) * 128 + rs] = v.z;
    hsT[(k + 3) * 128 + rs] = v.w;
  }
  int cg = t & 7, rg = t >> 3;   // rg 0..31 (4 rows each), cg 0..7 (8 cols)
  int cb = cg * 8;
  #pragma unroll 1
  for (int y = 0; y < 4; ++y) {
    const float* W = (y == 0) ? w0 : (y == 1) ? w1 : (y == 2) ? w2 : w3;
    const float* B = (y == 0) ? b0 : (y == 1) ? b1 : (y == 2) ? b2 : b3;
    __syncthreads();
    #pragma unroll
    for (int i = 0; i < 4; ++i)
      ((float4*)wsh)[t + i * 256] = ((const float4*)W)[t + i * 256];
    __syncthreads();
    float acc[4][8];
    #pragma unroll
    for (int r = 0; r < 4; ++r)
      #pragma unroll
      for (int j = 0; j < 8; ++j) acc[r][j] = 0.f;
    #pragma unroll 8
    for (int k = 0; k < 64; ++k) {
      float4 av = *(const float4*)&hsT[k * 128 + ((rg * 4) ^ SK(k))];
      float4 wv0 = *(const float4*)&wsh[k * 64 + cb];
      float4 wv1 = *(const float4*)&wsh[k * 64 + cb + 4];
      float a[4] = {av.x, av.y, av.z, av.w};
      float w[8] = {wv0.x, wv0.y, wv0.z, wv0.w, wv1.x, wv1.y, wv1.z, wv1.w};
      #pragma unroll
      for (int r = 0; r < 4; ++r)
        #pragma unroll
        for (int j = 0; j < 8; ++j) acc[r][j] += a[r] * w[j];
    }
    float4 bv0 = *(const float4*)(B + cb);
    float4 bv1 = *(const float4*)(B + cb + 4);
    float bv[8] = {bv0.x, bv0.y, bv0.z, bv0.w, bv1.x, bv1.y, bv1.z, bv1.w};
    __half* oh = (y == 1) ? Bh16 : (y == 2) ? Dh16 : Eh16;
    #pragma unroll
    for (int r = 0; r < 4; ++r) {
      int n = n0 + rg * 4 + r;
      if (n < NN) {
        float o[8];
        #pragma unroll
        for (int j = 0; j < 8; ++j) o[j] = acc[r][j] + bv[j];
        if (y == 0) {
          *(float4*)(Ah + (size_t)n * 64 + cb) = make_float4(o[0], o[1], o[2], o[3]);
          *(float4*)(Ah + (size_t)n * 64 + cb + 4) = make_float4(o[4], o[5], o[6], o[7]);
        } else {
          *(uint4*)(oh + (size_t)n * 64 + cb) = pk8(o);
        }
      }
    }
  }
}

// ---------------- fused edge kernel, 128-row tile, XOR-swizzled LDS, fp16 I/O --------
// MODE==1: e_new = e16 + relu(eh16_prev*sc+sh) during staging; EWRITE: write e16 back.
// ehat = e_new@Cw + Cb + Dh16[srcp] + Eh16[dstp]; store fp16; ESTATS: e-BN stats.
template <int MODE, int ESTATS, int EWRITE>
__global__ __launch_bounds__(256) void k_edge_f(__half* __restrict__ e16,
    __half* __restrict__ eh16,
    const float* __restrict__ Cw, const float* __restrict__ Cb,
    const int* __restrict__ srcp, const int* __restrict__ dstp,
    const __half* __restrict__ Dh16, const __half* __restrict__ Eh16,
    const float* __restrict__ bnp, double* __restrict__ stats) {
  __shared__ float esT[64 * 128];   // [k][row ^ SK(k)]
  __shared__ float cw[64 * 64];
  int t = threadIdx.x;
  int e0 = blockIdx.x * 128;
  #pragma unroll
  for (int i = 0; i < 4; ++i)
    ((float4*)cw)[t + i * 256] = ((const float4*)Cw)[t + i * 256];
  #pragma unroll
  for (int i = 0; i < 4; ++i) {
    int f = (t + i * 256) * 8;
    int r = f >> 6;          // 0..127
    int k = f & 63;          // multiple of 8
    size_t idx = (size_t)(e0 + r) * 64 + k;
    float v[8];
    up8(*(const uint4*)(e16 + idx), v);
    if (MODE == 1) {
      float pp[8];
      up8(*(const uint4*)(eh16 + idx), pp);
      float4 scA = *(const float4*)(bnp + 128 + k);
      float4 scB = *(const float4*)(bnp + 128 + k + 4);
      float4 shA = *(const float4*)(bnp + 192 + k);
      float4 shB = *(const float4*)(bnp + 192 + k + 4);
      float sc[8] = {scA.x, scA.y, scA.z, scA.w, scB.x, scB.y, scB.z, scB.w};
      float sh[8] = {shA.x, shA.y, shA.z, shA.w, shB.x, shB.y, shB.z, shB.w};
      #pragma unroll
      for (int j = 0; j < 8; ++j) v[j] += fmaxf(pp[j] * sc[j] + sh[j], 0.f);
      if (EWRITE) *(uint4*)(e16 + idx) = pk8(v);
    }
    int rs1 = r ^ SK(k);
    int rs2 = rs1 ^ 4;       // SK(k+4) == SK(k)+4 for k multiple of 8
    esT[(k + 0) * 128 + rs1] = v[0];
    esT[(k + 1) * 128 + rs1] = v[1];
    esT[(k + 2) * 128 + rs1] = v[2];
    esT[(k + 3) * 128 + rs1] = v[3];
    esT[(k + 4) * 128 + rs2] = v[4];
    esT[(k + 5) * 128 + rs2] = v[5];
    esT[(k + 6) * 128 + rs2] = v[6];
    esT[(k + 7) * 128 + rs2] = v[7];
  }
  __syncthreads();
  int cg = t & 7, rg = t >> 3;
  int cb = cg * 8;
  float acc[4][8];
  #pragma unroll
  for (int r = 0; r < 4; ++r)
    #pragma unroll
    for (int j = 0; j < 8; ++j) acc[r][j] = 0.f;
  #pragma unroll 8
  for (int k = 0; k < 64; ++k) {
    float4 av = *(const float4*)&esT[k * 128 + ((rg * 4) ^ SK(k))];
    float4 wv0 = *(const float4*)&cw[k * 64 + cb];
    float4 wv1 = *(const float4*)&cw[k * 64 + cb + 4];
    float a[4] = {av.x, av.y, av.z, av.w};
    float w[8] = {wv0.x, wv0.y, wv0.z, wv0.w, wv1.x, wv1.y, wv1.z, wv1.w};
    #pragma unroll
    for (int r = 0; r < 4; ++r)
      #pragma unroll
      for (int j = 0; j < 8; ++j) acc[r][j] += a[r] * w[j];
  }
  float4 cb0 = *(const float4*)(Cb + cb);
  float4 cb1 = *(const float4*)(Cb + cb + 4);
  float cbv[8] = {cb0.x, cb0.y, cb0.z, cb0.w, cb1.x, cb1.y, cb1.z, cb1.w};
  float psum[8], psq[8];
  #pragma unroll
  for (int j = 0; j < 8; ++j) { psum[j] = 0.f; psq[j] = 0.f; }
  #pragma unroll
  for (int r = 0; r < 4; ++r) {
    int p = e0 + rg * 4 + r;
    int sN = srcp[p], dN = dstp[p];
    float dd[8], qq[8];
    up8(*(const uint4*)(Dh16 + (size_t)sN * 64 + cb), dd);
    up8(*(const uint4*)(Eh16 + (size_t)dN * 64 + cb), qq);
    float ev[8];
    #pragma unroll
    for (int j = 0; j < 8; ++j) {
      float v = acc[r][j] + cbv[j] + dd[j] + qq[j];
      ev[j] = v;
      if (ESTATS) { psum[j] += v; psq[j] += v * v; }
    }
    *(uint4*)(eh16 + (size_t)p * 64 + cb) = pk8(ev);
  }
  if (ESTATS) {
    __syncthreads();  // esT reuse for stats reduce
    #pragma unroll
    for (int j = 0; j < 8; ++j) {
      esT[rg * 65 + cb + j] = psum[j];
      esT[2304 + rg * 65 + cb + j] = psq[j];
    }
    __syncthreads();
    if (t < 64) {
      float s = 0.f, q = 0.f;
      #pragma unroll
      for (int i = 0; i < 32; ++i) { s += esT[i * 65 + t]; q += esT[2304 + i * 65 + t]; }
      atomAddD(stats + 128 + t, (double)s);
      atomAddD(stats + 192 + t, (double)q);
    }
  }
}

// ---------------- aggregation (16 nodes/block), fp16 eh16/Bh16 ----------------
__global__ __launch_bounds__(256) void k_agg(const int* __restrict__ offs,
    const int* __restrict__ srcp, const __half* __restrict__ eh16,
    const __half* __restrict__ Bh16, float* __restrict__ Ah, double* __restrict__ stats) {
  int t = threadIdx.x;
  int c = t & 63;
  int g = t >> 6;
  float psum = 0.f, psq = 0.f;
  #pragma unroll 1
  for (int sub = 0; sub < 4; ++sub) {
    int n = blockIdx.x * 16 + g * 4 + sub;
    if (n < NN) {
      int i0 = offs[n], i1 = offs[n + 1];
      float num = 0.f, den = 0.f;
      int i = i0;
      #pragma unroll 1
      for (; i + 3 < i1; i += 4) {
        float x0 = __half2float(eh16[(size_t)(i + 0) * 64 + c]);
        float x1 = __half2float(eh16[(size_t)(i + 1) * 64 + c]);
        float x2 = __half2float(eh16[(size_t)(i + 2) * 64 + c]);
        float x3 = __half2float(eh16[(size_t)(i + 3) * 64 + c]);
        int s0 = srcp[i], s1 = srcp[i + 1], s2 = srcp[i + 2], s3 = srcp[i + 3];
        float b0 = __half2float(Bh16[(size_t)s0 * 64 + c]);
        float b1 = __half2float(Bh16[(size_t)s1 * 64 + c]);
        float b2 = __half2float(Bh16[(size_t)s2 * 64 + c]);
        float b3 = __half2float(Bh16[(size_t)s3 * 64 + c]);
        float g0 = 1.0f / (1.0f + __expf(-x0));
        float g1 = 1.0f / (1.0f + __expf(-x1));
        float g2 = 1.0f / (1.0f + __expf(-x2));
        float g3 = 1.0f / (1.0f + __expf(-x3));
        num += g0 * b0 + g1 * b1 + g2 * b2 + g3 * b3;
        den += g0 + g1 + g2 + g3;
      }
      #pragma unroll 1
      for (; i < i1; ++i) {
        float x0 = __half2float(eh16[(size_t)i * 64 + c]);
        int s0 = srcp[i];
        float b0 = __half2float(Bh16[(size_t)s0 * 64 + c]);
        float g0 = 1.0f / (1.0f + __expf(-x0));
        num += g0 * b0;
        den += g0;
      }
      float v = Ah[(size_t)n * 64 + c] + num / (den + 1e-6f);
      Ah[(size_t)n * 64 + c] = v;
      psum += v; psq += v * v;
    }
  }
  __shared__ float red[256];
  red[t] = psum; __syncthreads();
  if (t < 64) atomAddD(stats + t, (double)(red[t] + red[t + 64] + red[t + 128] + red[t + 192]));
  __syncthreads();
  red[t] = psq; __syncthreads();
  if (t < 64) atomAddD(stats + 64 + t, (double)(red[t] + red[t + 64] + red[t + 128] + red[t + 192]));
}

// ---------------- finalize BN scale/shift; zero stats for next layer ----------------
__global__ void k_bn_final(double* __restrict__ stats,
    const float* __restrict__ hgam, const float* __restrict__ hbet,
    const float* __restrict__ egam, const float* __restrict__ ebet,
    float* __restrict__ bnp) {
  int t = threadIdx.x;
  if (t < 64) {
    double mu = stats[t] * (1.0 / NN);
    double var = stats[64 + t] * (1.0 / NN) - mu * mu;
    float sc = hgam[t] / sqrtf((float)var + 1e-5f);
    bnp[t] = sc;
    bnp[64 + t] = hbet[t] - (float)mu * sc;
  } else if (t < 128) {
    int c = t - 64;
    double mu = stats[128 + c] * (1.0 / NE);
    double var = stats[192 + c] * (1.0 / NE) - mu * mu;
    float sc = egam[c] / sqrtf((float)var + 1e-5f);
    bnp[128 + c] = sc;
    bnp[192 + c] = ebet[c] - (float)mu * sc;
  }
  __syncthreads();
  stats[t] = 0.0;
  stats[t + 128] = 0.0;
}

// ---------------- readout with fused final h-residual ----------------
__global__ __launch_bounds__(256) void k_readout(const float* __restrict__ h,
    const float* __restrict__ Ah, const float* __restrict__ bnp,
    const int* __restrict__ gid, float* __restrict__ hg, float* __restrict__ counts) {
  int t = threadIdx.x;
  int c = t & 63;
  int ro = t >> 6;
  int nbase = blockIdx.x * 64;
  float sc = bnp[c], sh = bnp[64 + c];
  float sum = 0.f, cnt = 0.f;
  int curg = -1;
  #pragma unroll 1
  for (int i = 0; i < 16; ++i) {
    int n = nbase + ro + i * 4;
    if (n >= NN) break;
    int g = gid[n];
    if (g != curg) {
      if (curg >= 0) {
        atomAddF(&hg[curg * 64 + c], sum);
        if (c == 0) atomAddF(&counts[curg], cnt);
      }
      curg = g; sum = 0.f; cnt = 0.f;
    }
    size_t idx = (size_t)n * 64 + c;
    sum += h[idx] + fmaxf(Ah[idx] * sc + sh, 0.f);
    cnt += 1.f;
  }
  if (curg >= 0) {
    atomAddF(&hg[curg * 64 + c], sum);
    if (c == 0) atomAddF(&counts[curg], cnt);
  }
}

// ---------------- final MLP (16 graphs), one block ----------------
__global__ __launch_bounds__(256) void k_mlp(const float* __restrict__ hg, const float* __restrict__ counts,
    const float* __restrict__ state,
    const float* __restrict__ w1, const float* __restrict__ b1,
    const float* __restrict__ w2, const float* __restrict__ b2,
    const float* __restrict__ w3, const float* __restrict__ b3,
    float* __restrict__ out) {
  __shared__ float x0[16][68];
  __shared__ float x1[16][256];
  __shared__ float x2[16][256];
  int t = threadIdx.x;
  for (int idx = t; idx < 16 * 68; idx += 256) {
    int g = idx / 68, c = idx % 68;
    x0[g][c] = (c < 64) ? hg[g * 64 + c] / counts[g] : state[g * 4 + (c - 64)];
  }
  __syncthreads();
  {
    float acc[16];
    float bb = b1[t];
    #pragma unroll
    for (int g = 0; g < 16; ++g) acc[g] = bb;
    for (int k = 0; k < 68; ++k) {
      float w = w1[k * 256 + t];
      #pragma unroll
      for (int g = 0; g < 16; ++g) acc[g] += x0[g][k] * w;
    }
    #pragma unroll
    for (int g = 0; g < 16; ++g) x1[g][t] = fmaxf(acc[g], 0.f);
  }
  __syncthreads();
  {
    float acc[16];
    float bb = b2[t];
    #pragma unroll
    for (int g = 0; g < 16; ++g) acc[g] = bb;
    for (int k = 0; k < 256; ++k) {
      float w = w2[k * 256 + t];
      #pragma unroll
      for (int g = 0; g < 16; ++g) acc[g] += x1[g][k] * w;
    }
    #pragma unroll
    for (int g = 0; g < 16; ++g) x2[g][t] = fmaxf(acc[g], 0.f);
  }
  __syncthreads();
  if (t < 32) {
    int g = t >> 1, o = t & 1;
    float acc = b3[o];
    for (int k = 0; k < 256; ++k) acc += x2[g][k] * w3[k * 2 + o];
    out[g * 2 + o] = tanhf(acc);
  }
}

extern "C" void kernel_launch(void* const* d_in, const int* in_sizes, int n_in,
                              void* d_out, int out_size, void* d_ws, size_t ws_size,
                              hipStream_t stream) {
  const float* state   = (const float*)d_in[0];
  const float* h_feat  = (const float*)d_in[1];
  const float* e_feat  = (const float*)d_in[2];
  const int*   src     = (const int*)d_in[3];
  const int*   dst     = (const int*)d_in[4];
  const int*   gid     = (const int*)d_in[5];
  const float* emb_h_w = (const float*)d_in[6];
  const float* emb_h_b = (const float*)d_in[7];
  const float* emb_e_w = (const float*)d_in[8];
  const float* emb_e_b = (const float*)d_in[9];
  const float* A_w = (const float*)d_in[10];
  const float* A_b = (const float*)d_in[11];
  const float* B_w = (const float*)d_in[12];
  const float* B_b = (const float*)d_in[13];
  const float* C_w = (const float*)d_in[14];
  const float* C_b = (const float*)d_in[15];
  const float* D_w = (const float*)d_in[16];
  const float* D_b = (const float*)d_in[17];
  const float* E_w = (const float*)d_in[18];
  const float* E_b = (const float*)d_in[19];
  const float* bn_h_g = (const float*)d_in[20];
  const float* bn_h_b = (const float*)d_in[21];
  const float* bn_e_g = (const float*)d_in[22];
  const float* bn_e_b = (const float*)d_in[23];
  const float* l1_w = (const float*)d_in[24];
  const float* l1_b = (const float*)d_in[25];
  const float* l2_w = (const float*)d_in[26];
  const float* l2_b = (const float*)d_in[27];
  const float* l3_w = (const float*)d_in[28];
  const float* l3_b = (const float*)d_in[29];

  float* wsp = (float*)d_ws;

  const size_t F_H = (size_t)NN * 64;       // fp32 node array (floats)
  const size_t F_H2 = (size_t)NN * 32;      // fp16 node array (float units)
  const size_t F_E2 = (size_t)NE * 32;      // fp16 edge array (float units)
  size_t off = 0;
  float*  h     = wsp + off; off += F_H;
  float*  Ah    = wsp + off; off += F_H;
  __half* e16   = (__half*)(wsp + off); off += F_E2;
  __half* eh16  = (__half*)(wsp + off); off += F_E2;
  float*  ef2   = (float*)eh16;  // overlay: raw CSR e_feat pairs (consumed before eh16 writes)
  __half* Bh16  = (__half*)(wsp + off); off += F_H2;
  __half* Dh16  = (__half*)(wsp + off); off += F_H2;
  __half* Eh16  = (__half*)(wsp + off); off += F_H2;
  int* srcp    = (int*)(wsp + off); off += NE;
  int* dstp    = (int*)(wsp + off); off += NE;
  int* offs    = (int*)(wsp + off); off += NN + 4;
  int* degcur  = (int*)(wsp + off); off += NN;
  double* stats = (double*)(wsp + off); off += 512;
  float* bnp    = wsp + off; off += 256;
  float* hg     = wsp + off; off += 1024;
  float* counts = hg + 1024; off += 16;
  const size_t need = off * sizeof(float);
  if (ws_size < need) return;

  // CSR build + embeds
  k_zero<<<64, 256, 0, stream>>>((float4*)degcur, NN / 4);
  k_deg<<<(NE + 255) / 256, 256, 0, stream>>>(dst, degcur);
  k_scan<<<1, 1024, 0, stream>>>(degcur, offs, stats);
  k_scatter<<<(NE + 255) / 256, 256, 0, stream>>>(dst, src, e_feat, degcur, srcp, dstp, ef2);
  k_embed_e<<<(NE * 8 + 255) / 256, 256, 0, stream>>>(ef2, emb_e_w, emb_e_b, e16);
  k_embed_h<<<(NN * 16 + 255) / 256, 256, 0, stream>>>(h_feat, emb_h_w, emb_h_b, h);

  const int GN = (NN + 127) / 128;
  const int GE = NE / 128;
  for (int l = 0; l < 3; ++l) {
    if (l == 0)
      k_node_gemm<0><<<GN, 256, 0, stream>>>(h, Ah, bnp,
          A_w, B_w, D_w, E_w, A_b, B_b, D_b, E_b, Ah, Bh16, Dh16, Eh16);
    else
      k_node_gemm<1><<<GN, 256, 0, stream>>>(h, Ah, bnp,
          A_w + l * 4096, B_w + l * 4096, D_w + l * 4096, E_w + l * 4096,
          A_b + l * 64, B_b + l * 64, D_b + l * 64, E_b + l * 64,
          Ah, Bh16, Dh16, Eh16);
    if (l == 0)
      k_edge_f<0, 1, 0><<<GE, 256, 0, stream>>>(e16, eh16, C_w, C_b,
          srcp, dstp, Dh16, Eh16, bnp, stats);
    else if (l == 1)
      k_edge_f<1, 1, 1><<<GE, 256, 0, stream>>>(e16, eh16, C_w + 4096, C_b + 64,
          srcp, dstp, Dh16, Eh16, bnp, stats);
    else
      k_edge_f<1, 0, 0><<<GE, 256, 0, stream>>>(e16, eh16, C_w + 8192, C_b + 128,
          srcp, dstp, Dh16, Eh16, bnp, stats);
    k_agg<<<(NN + 15) / 16, 256, 0, stream>>>(offs, srcp, eh16, Bh16, Ah, stats);
    k_bn_final<<<1, 128, 0, stream>>>(stats, bn_h_g + l * 64, bn_h_b + l * 64,
        bn_e_g + l * 64, bn_e_b + l * 64, bnp);
  }
  k_zero<<<2, 256, 0, stream>>>((float4*)hg, (1024 + 16) / 4);
  k_readout<<<(NN + 63) / 64, 256, 0, stream>>>(h, Ah, bnp, gid, hg, counts);
  k_mlp<<<1, 256, 0, stream>>>(hg, counts, state,
      l1_w, l1_b, l2_w, l2_b, l3_w, l3_b, (float*)d_out);
}